// Round 1
// baseline (694.515 us; speedup 1.0000x reference)
//
#include <hip/hip_runtime.h>
#include <hip/hip_cooperative_groups.h>
#include <math.h>

namespace cg = cooperative_groups;

// Problem constants (fixed by reference setup_inputs)
constexpr int Nn = 2, Hh = 8, Ll = 2048, Dd = 64;
constexpr int S  = Nn * Hh;      // 16 sequences
constexpr int C  = 64;           // chunk length
constexpr int NC = Ll / C;       // 32 chunks/seq
constexpr int SC = S * NC;       // 512 chunk-blocks

constexpr int SB  = 72;          // bf16 LDS row stride (144 B rows, 16B-aligned)
constexpr int SRP = 65;          // fp32 score-matrix stride

#define EPSF 1e-6f

typedef __attribute__((ext_vector_type(8))) short short8;
typedef __attribute__((ext_vector_type(4))) float f32x4;
#define MFMA16(a, b, c) __builtin_amdgcn_mfma_f32_16x16x32_bf16(a, b, c, 0, 0, 0)

__device__ __forceinline__ float rcpf(float x) { return __builtin_amdgcn_rcpf(x); }
__device__ __forceinline__ float sigf(float x) { return rcpf(1.0f + __expf(-x)); }

__device__ __forceinline__ float waveRed(float v) {
#pragma unroll
    for (int off = 32; off > 0; off >>= 1) v += __shfl_xor(v, off, 64);
    return v;
}

__device__ __forceinline__ int gidx(int n, int l, int h, int d) {
    return ((n * Ll + l) * Hh + h) * Dd + d;
}

__device__ __forceinline__ float fc(const float4& v, int u) { return ((const float*)&v)[u]; }

__device__ __forceinline__ unsigned short f2bf(float x) {
    unsigned int u = __float_as_uint(x);
    unsigned int r = (u + 0x7fffu + ((u >> 16) & 1u)) >> 16;   // RNE
    return (unsigned short)r;
}
__device__ __forceinline__ unsigned int pack2(float lo, float hi) {
    return (unsigned int)f2bf(lo) | ((unsigned int)f2bf(hi) << 16);
}
__device__ __forceinline__ float bf2f(unsigned short u) {
    return __uint_as_float(((unsigned int)u) << 16);
}
__device__ __forceinline__ float lo16(unsigned int x) { return __uint_as_float(x << 16); }
__device__ __forceinline__ float hi16(unsigned int x) { return __uint_as_float(x & 0xffff0000u); }
__device__ __forceinline__ void unpack8(const uint4& v, float* o) {
    o[0] = lo16(v.x); o[1] = hi16(v.x); o[2] = lo16(v.y); o[3] = hi16(v.y);
    o[4] = lo16(v.z); o[5] = hi16(v.z); o[6] = lo16(v.w); o[7] = hi16(v.w);
}

// One cooperative kernel; block b owns chunk (s=b/NC, c=b%NC) for all phases.
// LDS: 4x bf16 tile (9216B) + P (16640B) + scratch ≈ 57.3 KB -> 2 blocks/CU -> 512 co-resident.
__global__ __launch_bounds__(256, 2) void k_fused(
        const float* __restrict__ Q, const float* __restrict__ K,
        const float* __restrict__ V,
        float* __restrict__ SK, float* __restrict__ SQ,
        float* __restrict__ SKso, float* __restrict__ SQsi,
        float* __restrict__ Tcs, float* __restrict__ KVT,
        float* __restrict__ Out) {
    __shared__ __align__(16) unsigned short sqB[C * SB];   // sigmoid(Q) rows [i][d] (whole kernel)
    __shared__ __align__(16) unsigned short skB[C * SB];   // sigmoid(K) rows; phase F: KV-prefix rows [m][d]
    __shared__ __align__(16) unsigned short vsT[C * SB];   // raw V^T [m][j] (whole kernel)
    __shared__ __align__(16) unsigned short xB[C * SB];    // phase D: K^T [d][i]; phase F: masked P*scomp
    __shared__ float P[C * SRP];                           // phase A: scratch(2048) then scores [i][j]
    __shared__ float scrP[512];
    __shared__ float colK[C], colQ[C], pk[Dd], pq[Dd];
    __shared__ float lsi[C], lso[C], rw1[C], rw2[C];
    __shared__ float le[C], ecum[C], lsc[C], s2l[C];
    __shared__ float pcsv;

    cg::grid_group grid = cg::this_grid();

    const int b = blockIdx.x, s = b / NC, c = b % NC;
    const int n = s / Hh, h = s % Hh, t = threadIdx.x;
    const int w = t >> 6, lane = t & 63, mf = lane & 15, qq = lane >> 4;
    const int I0 = 16 * w;
    (void)w;

    // ================= Phase A: stage + sigmoid + chunk sums + V^T + P MFMA =================
    {
        int d0 = (4 * t) & 63, ig = t >> 4;
        float psk[4] = {0, 0, 0, 0}, psq[4] = {0, 0, 0, 0};
#pragma unroll
        for (int j = 0; j < 4; j++) {
            int i = ig + 16 * j;
            int id = gidx(n, c * C + i, h, d0);
            float4 q4 = *(const float4*)&Q[id];
            float4 k4 = *(const float4*)&K[id];
            float a0 = sigf(q4.x), a1 = sigf(q4.y), a2 = sigf(q4.z), a3 = sigf(q4.w);
            float b0 = sigf(k4.x), b1 = sigf(k4.y), b2 = sigf(k4.z), b3 = sigf(k4.w);
            *(uint2*)&sqB[i * SB + d0] = make_uint2(pack2(a0, a1), pack2(a2, a3));
            *(uint2*)&skB[i * SB + d0] = make_uint2(pack2(b0, b1), pack2(b2, b3));
            psq[0] += a0; psq[1] += a1; psq[2] += a2; psq[3] += a3;
            psk[0] += b0; psk[1] += b1; psk[2] += b2; psk[3] += b3;
        }
#pragma unroll
        for (int r = 0; r < 4; r++) {           // per-d column-sum partials into P scratch
            P[ig * 64 + d0 + r] = psk[r];
            P[1024 + ig * 64 + d0 + r] = psq[r];
        }
        // raw V^T [m][j] directly from global (same pattern as old k_stage)
        int i0 = (t & 15) * 4, dt = (t >> 4) * 4;
        float4 vr[4];
#pragma unroll
        for (int r = 0; r < 4; r++) vr[r] = *(const float4*)&V[gidx(n, c * C + i0 + r, h, dt)];
#pragma unroll
        for (int u = 0; u < 4; u++)
            *(uint2*)&vsT[(dt + u) * SB + i0] = make_uint2(
                pack2(fc(vr[0], u), fc(vr[1], u)), pack2(fc(vr[2], u), fc(vr[3], u)));
    }
    __syncthreads();
    if (t < 64) {           // SK chunk sums -> global
        float v = 0.f;
#pragma unroll
        for (int g = 0; g < 16; g++) v += P[g * 64 + t];
        SK[b * 64 + t] = v;
    } else if (t < 128) {   // SQ chunk sums -> global
        int d = t - 64; float v = 0.f;
#pragma unroll
        for (int g = 0; g < 16; g++) v += P[1024 + g * 64 + d];
        SQ[b * 64 + d] = v;
    }
    {   // per-row sums colK/colQ (4 lanes/row)
        int i = t >> 2, g = t & 3;
        float ck = 0.f, cq = 0.f;
#pragma unroll
        for (int u = 0; u < 16; u++) {
            int d = g * 16 + u;
            ck += bf2f(skB[i * SB + d]);
            cq += bf2f(sqB[i * SB + d]);
        }
        ck += __shfl_xor(ck, 1, 64); ck += __shfl_xor(ck, 2, 64);
        cq += __shfl_xor(cq, 1, 64); cq += __shfl_xor(cq, 2, 64);
        if (g == 0) { colK[i] = ck; colQ[i] = cq; }
    }
    __syncthreads();        // P-scratch consumed before MFMA overwrites P
    {   // P = sq · sk^T (kept in LDS for phases B and F)
        f32x4 acc[4] = {{0,0,0,0},{0,0,0,0},{0,0,0,0},{0,0,0,0}};
#pragma unroll
        for (int kk = 0; kk < 64; kk += 32) {
            short8 a = *(const short8*)&sqB[(I0 + mf) * SB + kk + qq * 8];
#pragma unroll
            for (int J = 0; J < 4; J++) {
                short8 bb = *(const short8*)&skB[(16 * J + mf) * SB + kk + qq * 8];
                acc[J] = MFMA16(a, bb, acc[J]);
            }
        }
#pragma unroll
        for (int J = 0; J < 4; J++)
#pragma unroll
            for (int r = 0; r < 4; r++)
                P[(I0 + 4 * qq + r) * SRP + 16 * J + mf] = acc[J][r];
    }
    __threadfence();
    grid.sync();            // SK/SQ visible grid-wide
    __threadfence();

    // ================= Phase B: si/so, rw1/rw2, SKso/SQsi =================
    {
        int d = t & 63, g = t >> 6;
        float pa = 0.f, pb = 0.f;
        for (int cp = g; cp < c; cp += 4) {
            pa += SK[(s * NC + cp) * 64 + d];
            pb += SQ[(s * NC + cp) * 64 + d];
        }
        scrP[g * 64 + d] = pa;
        scrP[256 + g * 64 + d] = pb;
    }
    __syncthreads();
    if (t < 64) pk[t] = scrP[t] + scrP[64 + t] + scrP[128 + t] + scrP[192 + t];
    else if (t < 128) {
        int d = t - 64;
        pq[d] = scrP[256 + d] + scrP[320 + d] + scrP[384 + d] + scrP[448 + d];
    }
    __syncthreads();
    {   // si/so: 4 lanes per row
        int i = t >> 2, g = t & 3, l = c * C + i;
        float r1 = 0.f, r2 = 0.f;
        for (int jj = g; jj <= i; jj += 4) {
            r1 += P[i * SRP + jj] + EPSF * colK[jj];
            r2 += P[jj * SRP + i] + EPSF * colQ[jj];
        }
        float b1 = 0.f, b2 = 0.f;
#pragma unroll
        for (int u = 0; u < 16; u++) {
            int d = g * 16 + u;
            b1 += (bf2f(sqB[i * SB + d]) + EPSF) * (pk[d] + EPSF);
            b2 += (bf2f(skB[i * SB + d]) + EPSF) * (pq[d] + EPSF);
        }
        r1 += __shfl_xor(r1, 1, 64); r1 += __shfl_xor(r1, 2, 64);
        r2 += __shfl_xor(r2, 1, 64); r2 += __shfl_xor(r2, 2, 64);
        b1 += __shfl_xor(b1, 1, 64); b1 += __shfl_xor(b1, 2, 64);
        b2 += __shfl_xor(b2, 1, 64); b2 += __shfl_xor(b2, 2, 64);
        if (g == 0) {
            float nf = (float)(l + 1);
            lsi[i] = nf * rcpf(b1 + r1);
            lso[i] = nf * rcpf(b2 + r2);
        }
    }
    __syncthreads();
    {   // rw1/rw2 (kept in LDS)
        int i = t >> 2, g = t & 3;
        float a1 = 0.f, a2 = 0.f;
        for (int jj = g; jj <= i; jj += 4) {
            a1 += lso[jj] * (P[i * SRP + jj] + EPSF * colK[jj]);
            a2 += lsi[jj] * (P[jj * SRP + i] + EPSF * colQ[jj]);
        }
        a1 += __shfl_xor(a1, 1, 64); a1 += __shfl_xor(a1, 2, 64);
        a2 += __shfl_xor(a2, 1, 64); a2 += __shfl_xor(a2, 2, 64);
        if (g == 0) { rw1[i] = a1; rw2[i] = a2; }
    }
    {   // SKso/SQsi -> global
        int d = t >> 2, g = t & 3;
        float v1 = 0.f, v2 = 0.f;
#pragma unroll
        for (int u = 0; u < 16; u++) {
            int i = g * 16 + u;
            v1 += bf2f(skB[i * SB + d]) * lso[i];
            v2 += bf2f(sqB[i * SB + d]) * lsi[i];
        }
        v1 += __shfl_xor(v1, 1, 64); v1 += __shfl_xor(v1, 2, 64);
        v2 += __shfl_xor(v2, 1, 64); v2 += __shfl_xor(v2, 2, 64);
        if (g == 0) { SKso[b * 64 + d] = v1; SQsi[b * 64 + d] = v2; }
    }
    __threadfence();
    grid.sync();            // SKso/SQsi visible
    __threadfence();

    // ================= Phase C: cs/csr, e, sal, s2, ecum, Tcs =================
    {
        int d = t & 63, g = t >> 6;
        float pa = 0.f, pb = 0.f;
        for (int cp = g; cp < c; cp += 4) {
            pa += SKso[(s * NC + cp) * 64 + d];
            pb += SQsi[(s * NC + cp) * 64 + d];
        }
        scrP[g * 64 + d] = pa;
        scrP[256 + g * 64 + d] = pb;
    }
    __syncthreads();
    if (t < 64) pk[t] = scrP[t] + scrP[64 + t] + scrP[128 + t] + scrP[192 + t];
    else if (t < 128) {
        int d = t - 64;
        pq[d] = scrP[256 + d] + scrP[320 + d] + scrP[384 + d] + scrP[448 + d];
    }
    __syncthreads();
    {
        int i = t >> 2, g = t & 3, l = c * C + i;
        float b1 = 0.f, b2 = 0.f;
#pragma unroll
        for (int j = 0; j < 2; j++) {
            uint4 xq = *(const uint4*)&sqB[i * SB + g * 16 + 8 * j];
            uint4 xk = *(const uint4*)&skB[i * SB + g * 16 + 8 * j];
            float qa[8], ka[8];
            unpack8(xq, qa); unpack8(xk, ka);
            int d = g * 16 + 8 * j;
#pragma unroll
            for (int u = 0; u < 8; u++) {
                b1 += (qa[u] + EPSF) * (pk[d + u] + EPSF);
                b2 += (ka[u] + EPSF) * (pq[d + u] + EPSF);
            }
        }
        b1 += __shfl_xor(b1, 1, 64); b1 += __shfl_xor(b1, 2, 64);
        b2 += __shfl_xor(b2, 1, 64); b2 += __shfl_xor(b2, 2, 64);
        if (g == 0) {
            float nf = (float)(l + 1);
            float cs  = (b1 + rw1[i]) * rcpf(nf);
            float csr = (b2 + rw2[i]) * rcpf(nf);
            csr = fminf(fmaxf(csr, -1.f), 1.f);
            float e = __expf(csr);
            s2l[i] = lsi[i] * rcpf(nf) * sigf(cs);
            le[i] = e;
        }
    }
    __syncthreads();
    if (t < 64) {           // inclusive chunk-local scan of e; Tcs = chunk total
        float run = le[t];
#pragma unroll
        for (int off = 1; off < 64; off <<= 1) {
            float o = __shfl_up(run, off, 64);
            if (t >= off) run += o;
        }
        ecum[t] = run;
        if (t == 63) Tcs[b] = run;
    }
    __threadfence();
    grid.sync();            // Tcs visible
    __threadfence();

    // ================= Phase D: scomp + KVT chunk MFMA =================
    if (t < 64) {
        float v = (t < c) ? Tcs[s * NC + t] : 0.f;
        v = waveRed(v);
        if (t == 0) pcsv = v;
    }
    __syncthreads();
    if (t < 64) {
        int l = c * C + t;
        lsc[t] = le[t] * rcpf(pcsv + ecum[t]) * (float)(l + 1);
    }
    {   // K^T [d][i] built from skB into xB
        int i0 = (t & 15) * 4, dt = (t >> 4) * 4;
        uint2 kr[4];
#pragma unroll
        for (int r = 0; r < 4; r++) kr[r] = *(const uint2*)&skB[(i0 + r) * SB + dt];
#pragma unroll
        for (int u = 0; u < 4; u++) {
            unsigned int e0 = (u < 2 ? kr[0].x : kr[0].y), e1 = (u < 2 ? kr[1].x : kr[1].y);
            unsigned int e2 = (u < 2 ? kr[2].x : kr[2].y), e3 = (u < 2 ? kr[3].x : kr[3].y);
            int sh = (u & 1) * 16;
            unsigned int lo = ((e0 >> sh) & 0xffffu) | (((e1 >> sh) & 0xffffu) << 16);
            unsigned int hi = ((e2 >> sh) & 0xffffu) | (((e3 >> sh) & 0xffffu) << 16);
            *(uint2*)&xB[(dt + u) * SB + i0] = make_uint2(lo, hi);
        }
    }
    __syncthreads();
    {   // KVT[m][d] = sum_i (V^T[m][i]*scomp[i]) * K^T[d][i]; scale folded into A-fragments
        f32x4 acc[4] = {{0,0,0,0},{0,0,0,0},{0,0,0,0},{0,0,0,0}};
#pragma unroll
        for (int kk = 0; kk < 64; kk += 32) {
            short8 av = *(const short8*)&vsT[(I0 + mf) * SB + kk + qq * 8];
            short8 a;
#pragma unroll
            for (int u = 0; u < 8; u++)
                a[u] = (short)f2bf(bf2f((unsigned short)av[u]) * lsc[kk + qq * 8 + u]);
#pragma unroll
            for (int J = 0; J < 4; J++) {
                short8 bb = *(const short8*)&xB[(16 * J + mf) * SB + kk + qq * 8];
                acc[J] = MFMA16(a, bb, acc[J]);
            }
        }
#pragma unroll
        for (int J = 0; J < 4; J++)
#pragma unroll
            for (int r = 0; r < 4; r++)
                KVT[(size_t)b * 4096 + (I0 + 4 * qq + r) * 64 + 16 * J + mf] = acc[J][r];
    }
    __threadfence();
    grid.sync();            // all KVT chunks written
    __threadfence();

    // ================= Phase E: exclusive chunk-prefix of KVT (blocks 0..255) =================
    if (b < 256) {
        int ss = b >> 4, sub = b & 15;
        int e0 = sub * 256 + t;
        float x[NC];
#pragma unroll
        for (int cp = 0; cp < NC; cp++)
            x[cp] = KVT[(size_t)(ss * NC + cp) * 4096 + e0];
        float r = 0.f;
#pragma unroll
        for (int cp = 0; cp < NC; cp++) {
            float tv = x[cp];
            KVT[(size_t)(ss * NC + cp) * 4096 + e0] = r;
            r += tv;
        }
    }
    __threadfence();
    grid.sync();            // prefixed KVT visible
    __threadfence();

    // ================= Phase F: final two MFMAs + output =================
    {   // KV-prefix rows [m][d] -> skB (bf16)
#pragma unroll
        for (int j = 0; j < 4; j++) {
            int flat = 4 * t + 1024 * j, i = flat >> 6, d0 = flat & 63;
            float4 kv = *(const float4*)&KVT[(size_t)b * 4096 + flat];
            *(uint2*)&skB[i * SB + d0] = make_uint2(pack2(kv.x, kv.y), pack2(kv.z, kv.w));
        }
    }
    {   // masked P*scomp -> xB (bf16), from LDS-kept P (identical values to a recompute)
        int i = t >> 2, g = t & 3;
        unsigned int wds[8];
#pragma unroll
        for (int p = 0; p < 8; p++) {
            int j0 = g * 16 + 2 * p;
            float v0 = (j0     <= i) ? P[i * SRP + j0]     * lsc[j0]     : 0.f;
            float v1 = (j0 + 1 <= i) ? P[i * SRP + j0 + 1] * lsc[j0 + 1] : 0.f;
            wds[p] = pack2(v0, v1);
        }
        *(uint4*)&xB[i * SB + g * 16]     = make_uint4(wds[0], wds[1], wds[2], wds[3]);
        *(uint4*)&xB[i * SB + g * 16 + 8] = make_uint4(wds[4], wds[5], wds[6], wds[7]);
    }
    __syncthreads();
    {
        f32x4 acc[4] = {{0,0,0,0},{0,0,0,0},{0,0,0,0},{0,0,0,0}};
#pragma unroll
        for (int kk = 0; kk < 64; kk += 32) {   // mm1: sq · KVp ; mm2: stB · v
            short8 a1 = *(const short8*)&sqB[(I0 + mf) * SB + kk + qq * 8];
            short8 a2 = *(const short8*)&xB[(I0 + mf) * SB + kk + qq * 8];
#pragma unroll
            for (int J = 0; J < 4; J++) {
                short8 b1 = *(const short8*)&skB[(16 * J + mf) * SB + kk + qq * 8];
                acc[J] = MFMA16(a1, b1, acc[J]);
                short8 b2 = *(const short8*)&vsT[(16 * J + mf) * SB + kk + qq * 8];
                acc[J] = MFMA16(a2, b2, acc[J]);
            }
        }
#pragma unroll
        for (int J = 0; J < 4; J++)
#pragma unroll
            for (int r = 0; r < 4; r++) {
                int io = I0 + 4 * qq + r;
                Out[gidx(n, c * C + io, h, 16 * J + mf)] = acc[J][r] * s2l[io];
            }
    }
}

extern "C" void kernel_launch(void* const* d_in, const int* in_sizes, int n_in,
                              void* d_out, int out_size, void* d_ws, size_t ws_size,
                              hipStream_t stream) {
    const float* Q = (const float*)d_in[0];
    const float* K = (const float*)d_in[1];
    const float* V = (const float*)d_in[2];
    float* Out = (float*)d_out;

    float* ws   = (float*)d_ws;
    float* SK   = ws;                   // SC*64
    float* SQ   = SK   + SC * 64;
    float* SKso = SQ   + SC * 64;
    float* SQsi = SKso + SC * 64;
    float* Tcs  = SQsi + SC * 64;       // SC
    float* KVT  = Tcs  + SC;            // SC*4096

    void* args[] = {(void*)&Q, (void*)&K, (void*)&V,
                    (void*)&SK, (void*)&SQ, (void*)&SKso, (void*)&SQsi,
                    (void*)&Tcs, (void*)&KVT, (void*)&Out};
    hipLaunchCooperativeKernel((void*)k_fused, dim3(SC), dim3(256), args, 0, stream);
}

// Round 2
// 111.737 us; speedup vs baseline: 6.2156x; 6.2156x over previous
//
#include <hip/hip_runtime.h>
#include <math.h>

// Problem constants (fixed by reference setup_inputs)
constexpr int Nn = 2, Hh = 8, Ll = 2048, Dd = 64;
constexpr int S  = Nn * Hh;      // 16 sequences
constexpr int C  = 64;           // chunk length
constexpr int NC = Ll / C;       // 32 chunks/seq
constexpr int SC = S * NC;       // 512 chunk-blocks

constexpr int SB  = 72;          // bf16 LDS row stride (144 B rows, 16B-aligned)
constexpr int SRP = 65;          // fp32 score-matrix stride
constexpr int SS8 = 9;           // stride for 8-partial row-sum scratch

#define EPSF 1e-6f

typedef __attribute__((ext_vector_type(8))) short short8;
typedef __attribute__((ext_vector_type(4))) float f32x4;
#define MFMA16(a, b, c) __builtin_amdgcn_mfma_f32_16x16x32_bf16(a, b, c, 0, 0, 0)

__device__ __forceinline__ float rcpf(float x) { return __builtin_amdgcn_rcpf(x); }
// fast sigmoid: v_exp_f32 + v_rcp_f32 (~1ulp each; feeds bf16 — ample).
__device__ __forceinline__ float sigf(float x) { return rcpf(1.0f + __expf(-x)); }

__device__ __forceinline__ float waveRed(float v) {
#pragma unroll
    for (int off = 32; off > 0; off >>= 1) v += __shfl_xor(v, off, 64);
    return v;
}

__device__ __forceinline__ int gidx(int n, int l, int h, int d) {
    return ((n * Ll + l) * Hh + h) * Dd + d;
}

__device__ __forceinline__ float fc(const float4& v, int u) { return ((const float*)&v)[u]; }

__device__ __forceinline__ unsigned short f2bf(float x) {
    unsigned int u = __float_as_uint(x);
    unsigned int r = (u + 0x7fffu + ((u >> 16) & 1u)) >> 16;   // RNE
    return (unsigned short)r;
}
__device__ __forceinline__ unsigned int pack2(float lo, float hi) {
    return (unsigned int)f2bf(lo) | ((unsigned int)f2bf(hi) << 16);
}
__device__ __forceinline__ float bf2f(unsigned short u) {
    return __uint_as_float(((unsigned int)u) << 16);
}
__device__ __forceinline__ float lo16(unsigned int x) { return __uint_as_float(x << 16); }
__device__ __forceinline__ float hi16(unsigned int x) { return __uint_as_float(x & 0xffff0000u); }
__device__ __forceinline__ void unpack8(const uint4& v, float* o) {
    o[0] = lo16(v.x); o[1] = hi16(v.x); o[2] = lo16(v.y); o[3] = hi16(v.y);
    o[4] = lo16(v.z); o[5] = hi16(v.z); o[6] = lo16(v.w); o[7] = hi16(v.w);
}

// K1: stage — sigmoid ONCE, emit bf16 Qb/Kb (natural [i][d]), Kt/Vt (transposed [d][i]),
//     and per-chunk sums SK/SQ.
__global__ __launch_bounds__(256) void k_stage(const float* __restrict__ Q,
                                               const float* __restrict__ K,
                                               const float* __restrict__ V,
                                               unsigned short* __restrict__ Qb,
                                               unsigned short* __restrict__ Kb,
                                               unsigned short* __restrict__ Kt,
                                               unsigned short* __restrict__ Vt,
                                               float* __restrict__ SK,
                                               float* __restrict__ SQ) {
    __shared__ __align__(16) unsigned short skL[C * SB];
    __shared__ float scr[2048];
    int b = blockIdx.x, s = b / NC, c = b % NC;
    int n = s / Hh, h = s % Hh, t = threadIdx.x;
    int d0 = (4 * t) & 63, ig = t >> 4;
    size_t base = (size_t)b * 4096;
    float psk[4] = {0, 0, 0, 0}, psq[4] = {0, 0, 0, 0};
#pragma unroll
    for (int j = 0; j < 4; j++) {
        int i = ig + 16 * j;
        int id = gidx(n, c * C + i, h, d0);
        float4 q4 = *(const float4*)&Q[id];
        float4 k4 = *(const float4*)&K[id];
        float a0 = sigf(q4.x), a1 = sigf(q4.y), a2 = sigf(q4.z), a3 = sigf(q4.w);
        float b0 = sigf(k4.x), b1 = sigf(k4.y), b2 = sigf(k4.z), b3 = sigf(k4.w);
        uint2 pq2 = make_uint2(pack2(a0, a1), pack2(a2, a3));
        uint2 pk2 = make_uint2(pack2(b0, b1), pack2(b2, b3));
        *(uint2*)&Qb[base + i * 64 + d0] = pq2;
        *(uint2*)&Kb[base + i * 64 + d0] = pk2;
        *(uint2*)&skL[i * SB + d0] = pk2;
        psq[0] += a0; psq[1] += a1; psq[2] += a2; psq[3] += a3;
        psk[0] += b0; psk[1] += b1; psk[2] += b2; psk[3] += b3;
    }
#pragma unroll
    for (int r = 0; r < 4; r++) {
        scr[ig * 64 + d0 + r] = psk[r];
        scr[1024 + ig * 64 + d0 + r] = psq[r];
    }
    __syncthreads();
    if (t < 64) {
        float v = 0.f;
        for (int g = 0; g < 16; g++) v += scr[g * 64 + t];
        SK[b * 64 + t] = v;
    } else if (t < 128) {
        int d = t - 64; float v = 0.f;
        for (int g = 0; g < 16; g++) v += scr[1024 + g * 64 + d];
        SQ[b * 64 + d] = v;
    }
    // transposed outputs: K from LDS, V from global
    {
        int i0 = (t & 15) * 4, dt = (t >> 4) * 4;
        uint2 kr[4]; float4 vr[4];
#pragma unroll
        for (int r = 0; r < 4; r++) {
            kr[r] = *(const uint2*)&skL[(i0 + r) * SB + dt];
            vr[r] = *(const float4*)&V[gidx(n, c * C + i0 + r, h, dt)];
        }
#pragma unroll
        for (int u = 0; u < 4; u++) {
            unsigned int e0 = (u < 2 ? kr[0].x : kr[0].y), e1 = (u < 2 ? kr[1].x : kr[1].y);
            unsigned int e2 = (u < 2 ? kr[2].x : kr[2].y), e3 = (u < 2 ? kr[3].x : kr[3].y);
            int sh = (u & 1) * 16;
            unsigned int lo = ((e0 >> sh) & 0xffffu) | (((e1 >> sh) & 0xffffu) << 16);
            unsigned int hi = ((e2 >> sh) & 0xffffu) | (((e3 >> sh) & 0xffffu) << 16);
            *(uint2*)&Kt[base + (dt + u) * 64 + i0] = make_uint2(lo, hi);
            *(uint2*)&Vt[base + (dt + u) * 64 + i0] = make_uint2(
                pack2(fc(vr[0], u), fc(vr[1], u)), pack2(fc(vr[2], u), fc(vr[3], u)));
        }
    }
}

// K2: pass1 — row-copy bf16 staging, MFMA P (LDS only), si/so, rw1/rw2, SKso/SQsi.
__global__ __launch_bounds__(256) void k_pass1(const unsigned short* __restrict__ Qb,
                                               const unsigned short* __restrict__ Kb,
                                               const float* __restrict__ SK,
                                               const float* __restrict__ SQ,
                                               float* __restrict__ SKso,
                                               float* __restrict__ SQsi,
                                               float* __restrict__ si_g,
                                               float* __restrict__ rw1_g,
                                               float* __restrict__ rw2_g) {
    __shared__ __align__(16) unsigned short sqB[C * SB];
    __shared__ __align__(16) unsigned short skB[C * SB];
    __shared__ float P[C * SRP];
    __shared__ float scrA[C * SS8], scrB[C * SS8];
    __shared__ float colK[C], colQ[C], pk[Dd], pq[Dd], lsi[C], lso[C];
    int b = blockIdx.x, s = b / NC, c = b % NC, t = threadIdx.x;
    size_t base = (size_t)b * 4096;

#pragma unroll
    for (int j = 0; j < 2; j++) {
        int flat = 8 * t + 2048 * j, i = flat >> 6, d0 = flat & 63;
        uint4 xq = *(const uint4*)&Qb[base + flat];
        uint4 xk = *(const uint4*)&Kb[base + flat];
        *(uint4*)&sqB[i * SB + d0] = xq;
        *(uint4*)&skB[i * SB + d0] = xk;
        float qa[8], ka[8];
        unpack8(xq, qa); unpack8(xk, ka);
        float sq = 0.f, sk = 0.f;
#pragma unroll
        for (int u = 0; u < 8; u++) { sq += qa[u]; sk += ka[u]; }
        scrB[i * SS8 + (d0 >> 3)] = sq;
        scrA[i * SS8 + (d0 >> 3)] = sk;
    }
    {   // cross-chunk prefix partials (4 groups)
        int d = t & 63, g = t >> 6;
        float pa = 0.f, pb = 0.f;
        for (int cp = g; cp < c; cp += 4) {
            pa += SK[(s * NC + cp) * 64 + d];
            pb += SQ[(s * NC + cp) * 64 + d];
        }
        P[2048 + g * 64 + d] = pa;
        P[2304 + g * 64 + d] = pb;
    }
    __syncthreads();
    if (t < 64) {
        float v = 0.f;
#pragma unroll
        for (int u = 0; u < 8; u++) v += scrA[t * SS8 + u];
        colK[t] = v;
    } else if (t < 128) {
        int i = t - 64; float v = 0.f;
#pragma unroll
        for (int u = 0; u < 8; u++) v += scrB[i * SS8 + u];
        colQ[i] = v;
    } else if (t < 192) {
        int d = t - 128;
        pk[d] = P[2048 + d] + P[2112 + d] + P[2176 + d] + P[2240 + d];
    } else {
        int d = t - 192;
        pq[d] = P[2304 + d] + P[2368 + d] + P[2432 + d] + P[2496 + d];
    }
    __syncthreads();

    // MFMA: P = sq · sk^T
    {
        int w = t >> 6, lane = t & 63, m = lane & 15, q = lane >> 4;
        f32x4 acc[4] = {{0,0,0,0},{0,0,0,0},{0,0,0,0},{0,0,0,0}};
#pragma unroll
        for (int kk = 0; kk < 64; kk += 32) {
            short8 a = *(const short8*)&sqB[(16 * w + m) * SB + kk + q * 8];
#pragma unroll
            for (int J = 0; J < 4; J++) {
                short8 bb = *(const short8*)&skB[(16 * J + m) * SB + kk + q * 8];
                acc[J] = MFMA16(a, bb, acc[J]);
            }
        }
#pragma unroll
        for (int J = 0; J < 4; J++)
#pragma unroll
            for (int r = 0; r < 4; r++)
                P[(16 * w + 4 * q + r) * SRP + 16 * J + m] = acc[J][r];
    }
    __syncthreads();

    // si/so: 4 lanes per row
    {
        int i = t >> 2, g = t & 3, l = c * C + i;
        float r1 = 0.f, r2 = 0.f;
        for (int jj = g; jj <= i; jj += 4) {
            r1 += P[i * SRP + jj] + EPSF * colK[jj];
            r2 += P[jj * SRP + i] + EPSF * colQ[jj];
        }
        float b1 = 0.f, b2 = 0.f;
#pragma unroll
        for (int u = 0; u < 16; u++) {
            int d = g * 16 + u;
            b1 += (bf2f(sqB[i * SB + d]) + EPSF) * (pk[d] + EPSF);
            b2 += (bf2f(skB[i * SB + d]) + EPSF) * (pq[d] + EPSF);
        }
        r1 += __shfl_xor(r1, 1, 64); r1 += __shfl_xor(r1, 2, 64);
        r2 += __shfl_xor(r2, 1, 64); r2 += __shfl_xor(r2, 2, 64);
        b1 += __shfl_xor(b1, 1, 64); b1 += __shfl_xor(b1, 2, 64);
        b2 += __shfl_xor(b2, 1, 64); b2 += __shfl_xor(b2, 2, 64);
        if (g == 0) {
            float nf = (float)(l + 1);
            float siF = nf * rcpf(b1 + r1), soF = nf * rcpf(b2 + r2);
            si_g[s * Ll + l] = siF;
            lsi[i] = siF; lso[i] = soF;
        }
    }
    __syncthreads();

    // rw1/rw2: 4 lanes per row
    {
        int i = t >> 2, g = t & 3;
        float a1 = 0.f, a2 = 0.f;
        for (int jj = g; jj <= i; jj += 4) {
            a1 += lso[jj] * (P[i * SRP + jj] + EPSF * colK[jj]);
            a2 += lsi[jj] * (P[jj * SRP + i] + EPSF * colQ[jj]);
        }
        a1 += __shfl_xor(a1, 1, 64); a1 += __shfl_xor(a1, 2, 64);
        a2 += __shfl_xor(a2, 1, 64); a2 += __shfl_xor(a2, 2, 64);
        if (g == 0) {
            rw1_g[s * Ll + c * C + i] = a1;
            rw2_g[s * Ll + c * C + i] = a2;
        }
    }
    // SKso/SQsi: 4 lanes per d (16 i's each)
    {
        int d = t >> 2, g = t & 3;
        float v1 = 0.f, v2 = 0.f;
#pragma unroll
        for (int u = 0; u < 16; u++) {
            int i = g * 16 + u;
            v1 += bf2f(skB[i * SB + d]) * lso[i];
            v2 += bf2f(sqB[i * SB + d]) * lsi[i];
        }
        v1 += __shfl_xor(v1, 1, 64); v1 += __shfl_xor(v1, 2, 64);
        v2 += __shfl_xor(v2, 1, 64); v2 += __shfl_xor(v2, 2, 64);
        if (g == 0) {
            SKso[b * 64 + d] = v1;
            SQsi[b * 64 + d] = v2;
        }
    }
}

// K3: light pass2 — prefix + direct bf16 matvec.
__global__ __launch_bounds__(256) void k_pass2(const unsigned short* __restrict__ Qb,
                                               const unsigned short* __restrict__ Kb,
                                               const float* __restrict__ SKso,
                                               const float* __restrict__ SQsi,
                                               const float* __restrict__ si_g,
                                               const float* __restrict__ rw1_g,
                                               const float* __restrict__ rw2_g,
                                               float* __restrict__ s2_g,
                                               float* __restrict__ e_g,
                                               float* __restrict__ ecum_g,
                                               float* __restrict__ Tcs) {
    __shared__ float scr[512];
    __shared__ float pks[Dd], pqs[Dd], le[C];
    int b = blockIdx.x, s = b / NC, c = b % NC, t = threadIdx.x;

    {
        int d = t & 63, g = t >> 6;
        float pa = 0.f, pb = 0.f;
        for (int cp = g; cp < c; cp += 4) {
            pa += SKso[(s * NC + cp) * 64 + d];
            pb += SQsi[(s * NC + cp) * 64 + d];
        }
        scr[g * 64 + d] = pa;
        scr[256 + g * 64 + d] = pb;
    }
    __syncthreads();
    if (t < 64) pks[t] = scr[t] + scr[64 + t] + scr[128 + t] + scr[192 + t];
    else if (t < 128) {
        int d = t - 64;
        pqs[d] = scr[256 + d] + scr[320 + d] + scr[384 + d] + scr[448 + d];
    }
    __syncthreads();

    int i = t >> 2, g = t & 3, l = c * C + i;
    float b1 = 0.f, b2 = 0.f;
    size_t base = (size_t)b * 4096 + i * 64 + g * 16;
#pragma unroll
    for (int j = 0; j < 2; j++) {
        uint4 xq = *(const uint4*)&Qb[base + 8 * j];
        uint4 xk = *(const uint4*)&Kb[base + 8 * j];
        float qa[8], ka[8];
        unpack8(xq, qa); unpack8(xk, ka);
        int d = g * 16 + 8 * j;
#pragma unroll
        for (int u = 0; u < 8; u++) {
            b1 += (qa[u] + EPSF) * (pks[d + u] + EPSF);
            b2 += (ka[u] + EPSF) * (pqs[d + u] + EPSF);
        }
    }
    b1 += __shfl_xor(b1, 1, 64); b1 += __shfl_xor(b1, 2, 64);
    b2 += __shfl_xor(b2, 1, 64); b2 += __shfl_xor(b2, 2, 64);
    if (g == 0) {
        float nf = (float)(l + 1);
        float cs  = (b1 + rw1_g[s * Ll + l]) * rcpf(nf);
        float csr = (b2 + rw2_g[s * Ll + l]) * rcpf(nf);
        csr = fminf(fmaxf(csr, -1.f), 1.f);
        float e = __expf(csr);
        float sal = sigf(cs);
        s2_g[s * Ll + l] = si_g[s * Ll + l] * rcpf(nf) * sal;
        e_g[s * Ll + l] = e;
        le[i] = e;
    }
    __syncthreads();
    if (t < 64) {
        float run = le[t];
#pragma unroll
        for (int off = 1; off < 64; off <<= 1) {
            float o = __shfl_up(run, off, 64);
            if (t >= off) run += o;
        }
        ecum_g[s * Ll + c * C + t] = run;
        if (t == 63) Tcs[b] = run;
    }
}

// K4: scomp + MFMA chunk KV^T[m][d] (row-copy staging from Kt/Vt).
__global__ __launch_bounds__(256) void k_kv(const unsigned short* __restrict__ Kt,
                                            const unsigned short* __restrict__ Vt,
                                            const float* __restrict__ e_g,
                                            const float* __restrict__ ecum_g,
                                            const float* __restrict__ Tcs,
                                            float* __restrict__ scomp_g,
                                            float* __restrict__ KVT) {
    __shared__ __align__(16) unsigned short skT[C * SB];   // [d][i]
    __shared__ __align__(16) unsigned short vsT[C * SB];   // [m][i] scomp-scaled
    __shared__ float lsc[C];
    __shared__ float pcsv;
    int b = blockIdx.x, s = b / NC, c = b % NC, t = threadIdx.x;
    if (t < 64) {
        float v = (t < c) ? Tcs[s * NC + t] : 0.f;
        v = waveRed(v);
        if (t == 0) pcsv = v;
    }
    __syncthreads();
    if (t < 64) {
        int l = c * C + t;
        float ls = e_g[s * Ll + l] * rcpf(pcsv + ecum_g[s * Ll + l]) * (float)(l + 1);
        lsc[t] = ls;
        scomp_g[s * Ll + l] = ls;
    }
    __syncthreads();

    size_t base = (size_t)b * 4096;
#pragma unroll
    for (int j = 0; j < 2; j++) {
        int flat = 8 * t + 2048 * j, dR = flat >> 6, i0 = flat & 63;
        *(uint4*)&skT[dR * SB + i0] = *(const uint4*)&Kt[base + flat];
        uint4 vv = *(const uint4*)&Vt[base + flat];
        float x[8];
        unpack8(vv, x);
#pragma unroll
        for (int u = 0; u < 8; u++) x[u] *= lsc[i0 + u];
        uint4 o;
        o.x = pack2(x[0], x[1]); o.y = pack2(x[2], x[3]);
        o.z = pack2(x[4], x[5]); o.w = pack2(x[6], x[7]);
        *(uint4*)&vsT[dR * SB + i0] = o;
    }
    __syncthreads();

    {   // MFMA: KVT[m][d] = sum_i vsT[m][i] * skT[d][i]
        int w = t >> 6, lane = t & 63, m = lane & 15, q = lane >> 4;
        f32x4 acc[4] = {{0,0,0,0},{0,0,0,0},{0,0,0,0},{0,0,0,0}};
#pragma unroll
        for (int kk = 0; kk < 64; kk += 32) {
            short8 a = *(const short8*)&vsT[(16 * w + m) * SB + kk + q * 8];
#pragma unroll
            for (int J = 0; J < 4; J++) {
                short8 bb = *(const short8*)&skT[(16 * J + m) * SB + kk + q * 8];
                acc[J] = MFMA16(a, bb, acc[J]);
            }
        }
#pragma unroll
        for (int J = 0; J < 4; J++)
#pragma unroll
            for (int r = 0; r < 4; r++)
                KVT[(size_t)b * 4096 + (16 * w + 4 * q + r) * 64 + 16 * J + m] = acc[J][r];
    }
}

// K5: final — P recomputed via MFMA; KVT exclusive chunk-prefix computed INLINE
//     (ascending-order sum over cp<c, bit-identical to the old k_prefixKV+load).
//     Chunk order reversed within each sequence so heavy (high-c) blocks dispatch first.
__global__ __launch_bounds__(256) void k_final(const unsigned short* __restrict__ Qb,
                                               const unsigned short* __restrict__ Kb,
                                               const unsigned short* __restrict__ Vt,
                                               const float* __restrict__ s2_g,
                                               const float* __restrict__ scomp_g,
                                               const float* __restrict__ KVT,
                                               float* __restrict__ Out) {
    __shared__ __align__(16) unsigned short sqB[C * SB];    // [i][d]
    __shared__ __align__(16) unsigned short skB[C * SB];    // sk rows; later kvB [m][d]
    __shared__ __align__(16) unsigned short vsT[C * SB];    // [m][j] raw v
    __shared__ __align__(16) unsigned short stB[C * SB];    // [i][j] masked P*scomp
    __shared__ float lsc[C], s2l[C];
    int bb = blockIdx.x, s = bb / NC;
    int c = NC - 1 - (bb % NC);              // reversed: heavy blocks first
    int b = s * NC + c;
    int n = s / Hh, h = s % Hh, t = threadIdx.x;
    int w = t >> 6, lane = t & 63, mf = lane & 15, qq = lane >> 4;
    int I0 = 16 * w;

    if (t < 64) lsc[t] = scomp_g[s * Ll + c * C + t];
    else if (t < 128) s2l[t - 64] = s2_g[s * Ll + c * C + (t - 64)];

    // inline exclusive KVT prefix (reads stream through L2/L3; hidden behind staging + P-MFMA)
    float4 kvr[4] = {make_float4(0.f, 0.f, 0.f, 0.f), make_float4(0.f, 0.f, 0.f, 0.f),
                     make_float4(0.f, 0.f, 0.f, 0.f), make_float4(0.f, 0.f, 0.f, 0.f)};
    for (int cp = 0; cp < c; cp++) {
        const float* Kp = &KVT[(size_t)(s * NC + cp) * 4096];
#pragma unroll
        for (int j = 0; j < 4; j++) {
            float4 x = *(const float4*)&Kp[4 * t + 1024 * j];
            kvr[j].x += x.x; kvr[j].y += x.y; kvr[j].z += x.z; kvr[j].w += x.w;
        }
    }

    size_t base = (size_t)b * 4096;
#pragma unroll
    for (int j = 0; j < 2; j++) {
        int flat = 8 * t + 2048 * j, i = flat >> 6, d0 = flat & 63;
        *(uint4*)&sqB[i * SB + d0] = *(const uint4*)&Qb[base + flat];
        *(uint4*)&skB[i * SB + d0] = *(const uint4*)&Kb[base + flat];
        *(uint4*)&vsT[i * SB + d0] = *(const uint4*)&Vt[base + flat];
    }
    __syncthreads();

    // P recompute: wave w owns row-block I0; mask+scale -> stB
    {
        f32x4 acc[4] = {{0,0,0,0},{0,0,0,0},{0,0,0,0},{0,0,0,0}};
#pragma unroll
        for (int kk = 0; kk < 64; kk += 32) {
            short8 a = *(const short8*)&sqB[(I0 + mf) * SB + kk + qq * 8];
#pragma unroll
            for (int J = 0; J < 4; J++) {
                short8 bb2 = *(const short8*)&skB[(16 * J + mf) * SB + kk + qq * 8];
                acc[J] = MFMA16(a, bb2, acc[J]);
            }
        }
#pragma unroll
        for (int J = 0; J < 4; J++)
#pragma unroll
            for (int r = 0; r < 4; r++) {
                int i = I0 + 4 * qq + r, jj = 16 * J + mf;
                float v = (jj <= i) ? acc[J][r] * lsc[jj] : 0.f;
                stB[i * SB + jj] = f2bf(v);
            }
    }
    __syncthreads();   // skB reads done; stB ready

    // overlay kvB (= exclusive-prefix KV rows [m][d]) onto skB
#pragma unroll
    for (int j = 0; j < 4; j++) {
        int flat = 4 * t + 1024 * j, i = flat >> 6, d0 = flat & 63;
        *(uint2*)&skB[i * SB + d0] = make_uint2(pack2(kvr[j].x, kvr[j].y),
                                                pack2(kvr[j].z, kvr[j].w));
    }
    __syncthreads();

    f32x4 acc[4] = {{0,0,0,0},{0,0,0,0},{0,0,0,0},{0,0,0,0}};
#pragma unroll
    for (int kk = 0; kk < 64; kk += 32) {   // mm1: sq · KVp ; mm2: stB · v
        short8 a1 = *(const short8*)&sqB[(I0 + mf) * SB + kk + qq * 8];
        short8 a2 = *(const short8*)&stB[(I0 + mf) * SB + kk + qq * 8];
#pragma unroll
        for (int J = 0; J < 4; J++) {
            short8 b1 = *(const short8*)&skB[(16 * J + mf) * SB + kk + qq * 8];
            acc[J] = MFMA16(a1, b1, acc[J]);
            short8 b2 = *(const short8*)&vsT[(16 * J + mf) * SB + kk + qq * 8];
            acc[J] = MFMA16(a2, b2, acc[J]);
        }
    }
#pragma unroll
    for (int J = 0; J < 4; J++)
#pragma unroll
        for (int r = 0; r < 4; r++) {
            int io = I0 + 4 * qq + r;
            Out[gidx(n, c * C + io, h, 16 * J + mf)] = acc[J][r] * s2l[io];
        }
}

extern "C" void kernel_launch(void* const* d_in, const int* in_sizes, int n_in,
                              void* d_out, int out_size, void* d_ws, size_t ws_size,
                              hipStream_t stream) {
    const float* Q = (const float*)d_in[0];
    const float* K = (const float*)d_in[1];
    const float* V = (const float*)d_in[2];
    float* Out = (float*)d_out;

    float* ws    = (float*)d_ws;
    float* SK    = ws;                  // SC*64
    float* SQ    = SK    + SC * 64;
    float* SKso  = SQ    + SC * 64;
    float* SQsi  = SKso  + SC * 64;
    float* si_g  = SQsi  + SC * 64;     // S*Ll each
    float* rw1_g = si_g  + S * Ll;
    float* rw2_g = rw1_g + S * Ll;
    float* s2_g  = rw2_g + S * Ll;
    float* e_g   = s2_g  + S * Ll;
    float* ecum_g= e_g   + S * Ll;
    float* scomp = ecum_g+ S * Ll;
    float* Tcs   = scomp + S * Ll;      // SC
    float* KVT   = Tcs   + SC;          // SC*4096
    unsigned short* Qb = (unsigned short*)(KVT + (size_t)SC * 4096);   // SC*4096 bf16 each
    unsigned short* Kb = Qb + (size_t)SC * 4096;
    unsigned short* Kt = Kb + (size_t)SC * 4096;
    unsigned short* Vt = Kt + (size_t)SC * 4096;

    k_stage<<<SC, 256, 0, stream>>>(Q, K, V, Qb, Kb, Kt, Vt, SK, SQ);
    k_pass1<<<SC, 256, 0, stream>>>(Qb, Kb, SK, SQ, SKso, SQsi, si_g, rw1_g, rw2_g);
    k_pass2<<<SC, 256, 0, stream>>>(Qb, Kb, SKso, SQsi, si_g, rw1_g, rw2_g, s2_g, e_g, ecum_g, Tcs);
    k_kv<<<SC, 256, 0, stream>>>(Kt, Vt, e_g, ecum_g, Tcs, scomp, KVT);
    k_final<<<SC, 256, 0, stream>>>(Qb, Kb, Vt, s2_g, scomp, KVT, Out);
}

// Round 3
// 105.804 us; speedup vs baseline: 6.5642x; 1.0561x over previous
//
#include <hip/hip_runtime.h>
#include <math.h>

// Problem constants (fixed by reference setup_inputs)
constexpr int Nn = 2, Hh = 8, Ll = 2048, Dd = 64;
constexpr int S  = Nn * Hh;      // 16 sequences
constexpr int C  = 64;           // chunk length
constexpr int NC = Ll / C;       // 32 chunks/seq
constexpr int SC = S * NC;       // 512 chunk-blocks

constexpr int SB  = 72;          // bf16 LDS row stride (144 B rows, 16B-aligned)
constexpr int SRP = 65;          // fp32 score-matrix stride
constexpr int SS8 = 9;           // stride for 8-partial row-sum scratch

#define EPSF 1e-6f

typedef __attribute__((ext_vector_type(8))) short short8;
typedef __attribute__((ext_vector_type(4))) float f32x4;
#define MFMA16(a, b, c) __builtin_amdgcn_mfma_f32_16x16x32_bf16(a, b, c, 0, 0, 0)

__device__ __forceinline__ float rcpf(float x) { return __builtin_amdgcn_rcpf(x); }
// fast sigmoid: v_exp_f32 + v_rcp_f32 (~1ulp each; feeds bf16 — ample).
__device__ __forceinline__ float sigf(float x) { return rcpf(1.0f + __expf(-x)); }

__device__ __forceinline__ float waveRed(float v) {
#pragma unroll
    for (int off = 32; off > 0; off >>= 1) v += __shfl_xor(v, off, 64);
    return v;
}

__device__ __forceinline__ int gidx(int n, int l, int h, int d) {
    return ((n * Ll + l) * Hh + h) * Dd + d;
}

__device__ __forceinline__ float fc(const float4& v, int u) { return ((const float*)&v)[u]; }

__device__ __forceinline__ unsigned short f2bf(float x) {
    unsigned int u = __float_as_uint(x);
    unsigned int r = (u + 0x7fffu + ((u >> 16) & 1u)) >> 16;   // RNE
    return (unsigned short)r;
}
__device__ __forceinline__ unsigned int pack2(float lo, float hi) {
    return (unsigned int)f2bf(lo) | ((unsigned int)f2bf(hi) << 16);
}
__device__ __forceinline__ float bf2f(unsigned short u) {
    return __uint_as_float(((unsigned int)u) << 16);
}
__device__ __forceinline__ float lo16(unsigned int x) { return __uint_as_float(x << 16); }
__device__ __forceinline__ float hi16(unsigned int x) { return __uint_as_float(x & 0xffff0000u); }
__device__ __forceinline__ void unpack8(const uint4& v, float* o) {
    o[0] = lo16(v.x); o[1] = hi16(v.x); o[2] = lo16(v.y); o[3] = hi16(v.y);
    o[4] = lo16(v.z); o[5] = hi16(v.z); o[6] = lo16(v.w); o[7] = hi16(v.w);
}

// K1: stage — sigmoid ONCE, emit bf16 Qb/Kb (natural [i][d]), Vt (transposed [d][i]),
//     and per-chunk sums SK/SQ.  (Kt dropped: k_kv transposes Kb itself.)
__global__ __launch_bounds__(256) void k_stage(const float* __restrict__ Q,
                                               const float* __restrict__ K,
                                               const float* __restrict__ V,
                                               unsigned short* __restrict__ Qb,
                                               unsigned short* __restrict__ Kb,
                                               unsigned short* __restrict__ Vt,
                                               float* __restrict__ SK,
                                               float* __restrict__ SQ) {
    __shared__ float scr[2048];
    int b = blockIdx.x, s = b / NC, c = b % NC;
    int n = s / Hh, h = s % Hh, t = threadIdx.x;
    int d0 = (4 * t) & 63, ig = t >> 4;
    size_t base = (size_t)b * 4096;
    float psk[4] = {0, 0, 0, 0}, psq[4] = {0, 0, 0, 0};
#pragma unroll
    for (int j = 0; j < 4; j++) {
        int i = ig + 16 * j;
        int id = gidx(n, c * C + i, h, d0);
        float4 q4 = *(const float4*)&Q[id];
        float4 k4 = *(const float4*)&K[id];
        float a0 = sigf(q4.x), a1 = sigf(q4.y), a2 = sigf(q4.z), a3 = sigf(q4.w);
        float b0 = sigf(k4.x), b1 = sigf(k4.y), b2 = sigf(k4.z), b3 = sigf(k4.w);
        *(uint2*)&Qb[base + i * 64 + d0] = make_uint2(pack2(a0, a1), pack2(a2, a3));
        *(uint2*)&Kb[base + i * 64 + d0] = make_uint2(pack2(b0, b1), pack2(b2, b3));
        psq[0] += a0; psq[1] += a1; psq[2] += a2; psq[3] += a3;
        psk[0] += b0; psk[1] += b1; psk[2] += b2; psk[3] += b3;
    }
#pragma unroll
    for (int r = 0; r < 4; r++) {
        scr[ig * 64 + d0 + r] = psk[r];
        scr[1024 + ig * 64 + d0 + r] = psq[r];
    }
    __syncthreads();
    if (t < 64) {
        float v = 0.f;
        for (int g = 0; g < 16; g++) v += scr[g * 64 + t];
        SK[b * 64 + t] = v;
    } else if (t < 128) {
        int d = t - 64; float v = 0.f;
        for (int g = 0; g < 16; g++) v += scr[1024 + g * 64 + d];
        SQ[b * 64 + d] = v;
    }
    // transposed V output (from global, registers only)
    {
        int i0 = (t & 15) * 4, dt = (t >> 4) * 4;
        float4 vr[4];
#pragma unroll
        for (int r = 0; r < 4; r++)
            vr[r] = *(const float4*)&V[gidx(n, c * C + i0 + r, h, dt)];
#pragma unroll
        for (int u = 0; u < 4; u++)
            *(uint2*)&Vt[base + (dt + u) * 64 + i0] = make_uint2(
                pack2(fc(vr[0], u), fc(vr[1], u)), pack2(fc(vr[2], u), fc(vr[3], u)));
    }
}

// K2: pass1 — row-copy bf16 staging, MFMA P (LDS only), si/so, rw1/rw2, SKso/SQsi.
__global__ __launch_bounds__(256) void k_pass1(const unsigned short* __restrict__ Qb,
                                               const unsigned short* __restrict__ Kb,
                                               const float* __restrict__ SK,
                                               const float* __restrict__ SQ,
                                               float* __restrict__ SKso,
                                               float* __restrict__ SQsi,
                                               float* __restrict__ si_g,
                                               float* __restrict__ rw1_g,
                                               float* __restrict__ rw2_g) {
    __shared__ __align__(16) unsigned short sqB[C * SB];
    __shared__ __align__(16) unsigned short skB[C * SB];
    __shared__ float P[C * SRP];
    __shared__ float scrA[C * SS8], scrB[C * SS8];
    __shared__ float colK[C], colQ[C], pk[Dd], pq[Dd], lsi[C], lso[C];
    int b = blockIdx.x, s = b / NC, c = b % NC, t = threadIdx.x;
    size_t base = (size_t)b * 4096;

#pragma unroll
    for (int j = 0; j < 2; j++) {
        int flat = 8 * t + 2048 * j, i = flat >> 6, d0 = flat & 63;
        uint4 xq = *(const uint4*)&Qb[base + flat];
        uint4 xk = *(const uint4*)&Kb[base + flat];
        *(uint4*)&sqB[i * SB + d0] = xq;
        *(uint4*)&skB[i * SB + d0] = xk;
        float qa[8], ka[8];
        unpack8(xq, qa); unpack8(xk, ka);
        float sq = 0.f, sk = 0.f;
#pragma unroll
        for (int u = 0; u < 8; u++) { sq += qa[u]; sk += ka[u]; }
        scrB[i * SS8 + (d0 >> 3)] = sq;
        scrA[i * SS8 + (d0 >> 3)] = sk;
    }
    {   // cross-chunk prefix partials (4 groups)
        int d = t & 63, g = t >> 6;
        float pa = 0.f, pb = 0.f;
        for (int cp = g; cp < c; cp += 4) {
            pa += SK[(s * NC + cp) * 64 + d];
            pb += SQ[(s * NC + cp) * 64 + d];
        }
        P[2048 + g * 64 + d] = pa;
        P[2304 + g * 64 + d] = pb;
    }
    __syncthreads();
    if (t < 64) {
        float v = 0.f;
#pragma unroll
        for (int u = 0; u < 8; u++) v += scrA[t * SS8 + u];
        colK[t] = v;
    } else if (t < 128) {
        int i = t - 64; float v = 0.f;
#pragma unroll
        for (int u = 0; u < 8; u++) v += scrB[i * SS8 + u];
        colQ[i] = v;
    } else if (t < 192) {
        int d = t - 128;
        pk[d] = P[2048 + d] + P[2112 + d] + P[2176 + d] + P[2240 + d];
    } else {
        int d = t - 192;
        pq[d] = P[2304 + d] + P[2368 + d] + P[2432 + d] + P[2496 + d];
    }
    __syncthreads();

    // MFMA: P = sq · sk^T
    {
        int w = t >> 6, lane = t & 63, m = lane & 15, q = lane >> 4;
        f32x4 acc[4] = {{0,0,0,0},{0,0,0,0},{0,0,0,0},{0,0,0,0}};
#pragma unroll
        for (int kk = 0; kk < 64; kk += 32) {
            short8 a = *(const short8*)&sqB[(16 * w + m) * SB + kk + q * 8];
#pragma unroll
            for (int J = 0; J < 4; J++) {
                short8 bb = *(const short8*)&skB[(16 * J + m) * SB + kk + q * 8];
                acc[J] = MFMA16(a, bb, acc[J]);
            }
        }
#pragma unroll
        for (int J = 0; J < 4; J++)
#pragma unroll
            for (int r = 0; r < 4; r++)
                P[(16 * w + 4 * q + r) * SRP + 16 * J + m] = acc[J][r];
    }
    __syncthreads();

    // si/so: 4 lanes per row
    {
        int i = t >> 2, g = t & 3, l = c * C + i;
        float r1 = 0.f, r2 = 0.f;
        for (int jj = g; jj <= i; jj += 4) {
            r1 += P[i * SRP + jj] + EPSF * colK[jj];
            r2 += P[jj * SRP + i] + EPSF * colQ[jj];
        }
        float b1 = 0.f, b2 = 0.f;
#pragma unroll
        for (int u = 0; u < 16; u++) {
            int d = g * 16 + u;
            b1 += (bf2f(sqB[i * SB + d]) + EPSF) * (pk[d] + EPSF);
            b2 += (bf2f(skB[i * SB + d]) + EPSF) * (pq[d] + EPSF);
        }
        r1 += __shfl_xor(r1, 1, 64); r1 += __shfl_xor(r1, 2, 64);
        r2 += __shfl_xor(r2, 1, 64); r2 += __shfl_xor(r2, 2, 64);
        b1 += __shfl_xor(b1, 1, 64); b1 += __shfl_xor(b1, 2, 64);
        b2 += __shfl_xor(b2, 1, 64); b2 += __shfl_xor(b2, 2, 64);
        if (g == 0) {
            float nf = (float)(l + 1);
            float siF = nf * rcpf(b1 + r1), soF = nf * rcpf(b2 + r2);
            si_g[s * Ll + l] = siF;
            lsi[i] = siF; lso[i] = soF;
        }
    }
    __syncthreads();

    // rw1/rw2: 4 lanes per row
    {
        int i = t >> 2, g = t & 3;
        float a1 = 0.f, a2 = 0.f;
        for (int jj = g; jj <= i; jj += 4) {
            a1 += lso[jj] * (P[i * SRP + jj] + EPSF * colK[jj]);
            a2 += lsi[jj] * (P[jj * SRP + i] + EPSF * colQ[jj]);
        }
        a1 += __shfl_xor(a1, 1, 64); a1 += __shfl_xor(a1, 2, 64);
        a2 += __shfl_xor(a2, 1, 64); a2 += __shfl_xor(a2, 2, 64);
        if (g == 0) {
            rw1_g[s * Ll + c * C + i] = a1;
            rw2_g[s * Ll + c * C + i] = a2;
        }
    }
    // SKso/SQsi: 4 lanes per d (16 i's each)
    {
        int d = t >> 2, g = t & 3;
        float v1 = 0.f, v2 = 0.f;
#pragma unroll
        for (int u = 0; u < 16; u++) {
            int i = g * 16 + u;
            v1 += bf2f(skB[i * SB + d]) * lso[i];
            v2 += bf2f(sqB[i * SB + d]) * lsi[i];
        }
        v1 += __shfl_xor(v1, 1, 64); v1 += __shfl_xor(v1, 2, 64);
        v2 += __shfl_xor(v2, 1, 64); v2 += __shfl_xor(v2, 2, 64);
        if (g == 0) {
            SKso[b * 64 + d] = v1;
            SQsi[b * 64 + d] = v2;
        }
    }
}

// K3: light pass2 — prefix + direct bf16 matvec.
__global__ __launch_bounds__(256) void k_pass2(const unsigned short* __restrict__ Qb,
                                               const unsigned short* __restrict__ Kb,
                                               const float* __restrict__ SKso,
                                               const float* __restrict__ SQsi,
                                               const float* __restrict__ si_g,
                                               const float* __restrict__ rw1_g,
                                               const float* __restrict__ rw2_g,
                                               float* __restrict__ s2_g,
                                               float* __restrict__ e_g,
                                               float* __restrict__ ecum_g,
                                               float* __restrict__ Tcs) {
    __shared__ float scr[512];
    __shared__ float pks[Dd], pqs[Dd], le[C];
    int b = blockIdx.x, s = b / NC, c = b % NC, t = threadIdx.x;

    {
        int d = t & 63, g = t >> 6;
        float pa = 0.f, pb = 0.f;
        for (int cp = g; cp < c; cp += 4) {
            pa += SKso[(s * NC + cp) * 64 + d];
            pb += SQsi[(s * NC + cp) * 64 + d];
        }
        scr[g * 64 + d] = pa;
        scr[256 + g * 64 + d] = pb;
    }
    __syncthreads();
    if (t < 64) pks[t] = scr[t] + scr[64 + t] + scr[128 + t] + scr[192 + t];
    else if (t < 128) {
        int d = t - 64;
        pqs[d] = scr[256 + d] + scr[320 + d] + scr[384 + d] + scr[448 + d];
    }
    __syncthreads();

    int i = t >> 2, g = t & 3, l = c * C + i;
    float b1 = 0.f, b2 = 0.f;
    size_t base = (size_t)b * 4096 + i * 64 + g * 16;
#pragma unroll
    for (int j = 0; j < 2; j++) {
        uint4 xq = *(const uint4*)&Qb[base + 8 * j];
        uint4 xk = *(const uint4*)&Kb[base + 8 * j];
        float qa[8], ka[8];
        unpack8(xq, qa); unpack8(xk, ka);
        int d = g * 16 + 8 * j;
#pragma unroll
        for (int u = 0; u < 8; u++) {
            b1 += (qa[u] + EPSF) * (pks[d + u] + EPSF);
            b2 += (ka[u] + EPSF) * (pqs[d + u] + EPSF);
        }
    }
    b1 += __shfl_xor(b1, 1, 64); b1 += __shfl_xor(b1, 2, 64);
    b2 += __shfl_xor(b2, 1, 64); b2 += __shfl_xor(b2, 2, 64);
    if (g == 0) {
        float nf = (float)(l + 1);
        float cs  = (b1 + rw1_g[s * Ll + l]) * rcpf(nf);
        float csr = (b2 + rw2_g[s * Ll + l]) * rcpf(nf);
        csr = fminf(fmaxf(csr, -1.f), 1.f);
        float e = __expf(csr);
        float sal = sigf(cs);
        s2_g[s * Ll + l] = si_g[s * Ll + l] * rcpf(nf) * sal;
        e_g[s * Ll + l] = e;
        le[i] = e;
    }
    __syncthreads();
    if (t < 64) {
        float run = le[t];
#pragma unroll
        for (int off = 1; off < 64; off <<= 1) {
            float o = __shfl_up(run, off, 64);
            if (t >= off) run += o;
        }
        ecum_g[s * Ll + c * C + t] = run;
        if (t == 63) Tcs[b] = run;
    }
}

// K4: scomp + MFMA chunk KV^T[m][d].  K^T built in LDS from Kb (Kt array eliminated).
__global__ __launch_bounds__(256) void k_kv(const unsigned short* __restrict__ Kb,
                                            const unsigned short* __restrict__ Vt,
                                            const float* __restrict__ e_g,
                                            const float* __restrict__ ecum_g,
                                            const float* __restrict__ Tcs,
                                            float* __restrict__ scomp_g,
                                            float* __restrict__ KVT) {
    __shared__ __align__(16) unsigned short skL[C * SB];   // [i][d] rows from Kb
    __shared__ __align__(16) unsigned short skT[C * SB];   // [d][i]
    __shared__ __align__(16) unsigned short vsT[C * SB];   // [m][i] scomp-scaled
    __shared__ float lsc[C];
    __shared__ float pcsv;
    int b = blockIdx.x, s = b / NC, c = b % NC, t = threadIdx.x;
    size_t base = (size_t)b * 4096;

    // row-copy Kb -> skL (independent of scomp computation below)
#pragma unroll
    for (int j = 0; j < 2; j++) {
        int flat = 8 * t + 2048 * j, i = flat >> 6, d0 = flat & 63;
        *(uint4*)&skL[i * SB + d0] = *(const uint4*)&Kb[base + flat];
    }
    if (t < 64) {
        float v = (t < c) ? Tcs[s * NC + t] : 0.f;
        v = waveRed(v);
        if (t == 0) pcsv = v;
    }
    __syncthreads();
    if (t < 64) {
        int l = c * C + t;
        float ls = e_g[s * Ll + l] * rcpf(pcsv + ecum_g[s * Ll + l]) * (float)(l + 1);
        lsc[t] = ls;
        scomp_g[s * Ll + l] = ls;
    }
    __syncthreads();

    // vsT staging (scomp-scaled) + skL->skT bit-shuffle transpose
#pragma unroll
    for (int j = 0; j < 2; j++) {
        int flat = 8 * t + 2048 * j, dR = flat >> 6, i0 = flat & 63;
        uint4 vv = *(const uint4*)&Vt[base + flat];
        float x[8];
        unpack8(vv, x);
#pragma unroll
        for (int u = 0; u < 8; u++) x[u] *= lsc[i0 + u];
        uint4 o;
        o.x = pack2(x[0], x[1]); o.y = pack2(x[2], x[3]);
        o.z = pack2(x[4], x[5]); o.w = pack2(x[6], x[7]);
        *(uint4*)&vsT[dR * SB + i0] = o;
    }
    {
        int i0 = (t & 15) * 4, dt = (t >> 4) * 4;
        uint2 kr[4];
#pragma unroll
        for (int r = 0; r < 4; r++) kr[r] = *(const uint2*)&skL[(i0 + r) * SB + dt];
#pragma unroll
        for (int u = 0; u < 4; u++) {
            unsigned int e0 = (u < 2 ? kr[0].x : kr[0].y), e1 = (u < 2 ? kr[1].x : kr[1].y);
            unsigned int e2 = (u < 2 ? kr[2].x : kr[2].y), e3 = (u < 2 ? kr[3].x : kr[3].y);
            int sh = (u & 1) * 16;
            unsigned int lo = ((e0 >> sh) & 0xffffu) | (((e1 >> sh) & 0xffffu) << 16);
            unsigned int hi = ((e2 >> sh) & 0xffffu) | (((e3 >> sh) & 0xffffu) << 16);
            *(uint2*)&skT[(dt + u) * SB + i0] = make_uint2(lo, hi);
        }
    }
    __syncthreads();

    {   // MFMA: KVT[m][d] = sum_i vsT[m][i] * skT[d][i]
        int w = t >> 6, lane = t & 63, m = lane & 15, q = lane >> 4;
        f32x4 acc[4] = {{0,0,0,0},{0,0,0,0},{0,0,0,0},{0,0,0,0}};
#pragma unroll
        for (int kk = 0; kk < 64; kk += 32) {
            short8 a = *(const short8*)&vsT[(16 * w + m) * SB + kk + q * 8];
#pragma unroll
            for (int J = 0; J < 4; J++) {
                short8 bb = *(const short8*)&skT[(16 * J + m) * SB + kk + q * 8];
                acc[J] = MFMA16(a, bb, acc[J]);
            }
        }
#pragma unroll
        for (int J = 0; J < 4; J++)
#pragma unroll
            for (int r = 0; r < 4; r++)
                KVT[(size_t)b * 4096 + (16 * w + 4 * q + r) * 64 + 16 * J + m] = acc[J][r];
    }
}

// K5: exclusive chunk-prefix of KVT; f32 accumulation (same order as before), bf16 output.
//     The bf16 rounding here is the SAME RNE pack k_final previously applied -> bit-identical.
__global__ __launch_bounds__(256) void k_prefixKV(const float* __restrict__ KVT,
                                                  unsigned short* __restrict__ KVpb) {
    int bx = blockIdx.x, s = bx >> 3, sub = bx & 7;
    int e0 = sub * 512 + 2 * threadIdx.x;
    float2 x[NC];
#pragma unroll
    for (int cp = 0; cp < NC; cp++)
        x[cp] = *(const float2*)&KVT[(size_t)(s * NC + cp) * 4096 + e0];
    float r0 = 0.f, r1 = 0.f;
#pragma unroll
    for (int cp = 0; cp < NC; cp++) {
        *(unsigned int*)&KVpb[(size_t)(s * NC + cp) * 4096 + e0] = pack2(r0, r1);
        r0 += x[cp].x; r1 += x[cp].y;
    }
}

// K6: final — P recomputed via MFMA; prefix-KV read as bf16 rows (KVpb).
__global__ __launch_bounds__(256) void k_final(const unsigned short* __restrict__ Qb,
                                               const unsigned short* __restrict__ Kb,
                                               const unsigned short* __restrict__ Vt,
                                               const float* __restrict__ s2_g,
                                               const float* __restrict__ scomp_g,
                                               const unsigned short* __restrict__ KVpb,
                                               float* __restrict__ Out) {
    __shared__ __align__(16) unsigned short sqB[C * SB];    // [i][d]
    __shared__ __align__(16) unsigned short skB[C * SB];    // sk rows; later kvB [m][d]
    __shared__ __align__(16) unsigned short vsT[C * SB];    // [m][j] raw v
    __shared__ __align__(16) unsigned short stB[C * SB];    // [i][j] masked P*scomp
    __shared__ float lsc[C], s2l[C];
    int b = blockIdx.x, s = b / NC, c = b % NC;
    int n = s / Hh, h = s % Hh, t = threadIdx.x;
    int w = t >> 6, lane = t & 63, mf = lane & 15, qq = lane >> 4;
    int I0 = 16 * w;

    if (t < 64) lsc[t] = scomp_g[s * Ll + c * C + t];
    else if (t < 128) s2l[t - 64] = s2_g[s * Ll + c * C + (t - 64)];

    size_t base = (size_t)b * 4096;
    // early prefix-KV loads (hidden behind staging + P-MFMA)
    uint4 kvp[2];
#pragma unroll
    for (int j = 0; j < 2; j++)
        kvp[j] = *(const uint4*)&KVpb[base + 8 * t + 2048 * j];

#pragma unroll
    for (int j = 0; j < 2; j++) {
        int flat = 8 * t + 2048 * j, i = flat >> 6, d0 = flat & 63;
        *(uint4*)&sqB[i * SB + d0] = *(const uint4*)&Qb[base + flat];
        *(uint4*)&skB[i * SB + d0] = *(const uint4*)&Kb[base + flat];
        *(uint4*)&vsT[i * SB + d0] = *(const uint4*)&Vt[base + flat];
    }
    __syncthreads();

    // P recompute: wave w owns row-block I0; mask+scale -> stB
    {
        f32x4 acc[4] = {{0,0,0,0},{0,0,0,0},{0,0,0,0},{0,0,0,0}};
#pragma unroll
        for (int kk = 0; kk < 64; kk += 32) {
            short8 a = *(const short8*)&sqB[(I0 + mf) * SB + kk + qq * 8];
#pragma unroll
            for (int J = 0; J < 4; J++) {
                short8 bb2 = *(const short8*)&skB[(16 * J + mf) * SB + kk + qq * 8];
                acc[J] = MFMA16(a, bb2, acc[J]);
            }
        }
#pragma unroll
        for (int J = 0; J < 4; J++)
#pragma unroll
            for (int r = 0; r < 4; r++) {
                int i = I0 + 4 * qq + r, jj = 16 * J + mf;
                float v = (jj <= i) ? acc[J][r] * lsc[jj] : 0.f;
                stB[i * SB + jj] = f2bf(v);
            }
    }
    __syncthreads();   // skB reads done; stB ready

    // overlay kvB (= exclusive-prefix KV rows [m][d], already bf16) onto skB
#pragma unroll
    for (int j = 0; j < 2; j++) {
        int flat = 8 * t + 2048 * j, i = flat >> 6, d0 = flat & 63;
        *(uint4*)&skB[i * SB + d0] = kvp[j];
    }
    __syncthreads();

    f32x4 acc[4] = {{0,0,0,0},{0,0,0,0},{0,0,0,0},{0,0,0,0}};
#pragma unroll
    for (int kk = 0; kk < 64; kk += 32) {   // mm1: sq · KVp ; mm2: stB · v
        short8 a1 = *(const short8*)&sqB[(I0 + mf) * SB + kk + qq * 8];
        short8 a2 = *(const short8*)&stB[(I0 + mf) * SB + kk + qq * 8];
#pragma unroll
        for (int J = 0; J < 4; J++) {
            short8 b1 = *(const short8*)&skB[(16 * J + mf) * SB + kk + qq * 8];
            acc[J] = MFMA16(a1, b1, acc[J]);
            short8 b2 = *(const short8*)&vsT[(16 * J + mf) * SB + kk + qq * 8];
            acc[J] = MFMA16(a2, b2, acc[J]);
        }
    }
#pragma unroll
    for (int J = 0; J < 4; J++)
#pragma unroll
        for (int r = 0; r < 4; r++) {
            int io = I0 + 4 * qq + r;
            Out[gidx(n, c * C + io, h, 16 * J + mf)] = acc[J][r] * s2l[io];
        }
}

extern "C" void kernel_launch(void* const* d_in, const int* in_sizes, int n_in,
                              void* d_out, int out_size, void* d_ws, size_t ws_size,
                              hipStream_t stream) {
    const float* Q = (const float*)d_in[0];
    const float* K = (const float*)d_in[1];
    const float* V = (const float*)d_in[2];
    float* Out = (float*)d_out;

    float* ws    = (float*)d_ws;
    float* SK    = ws;                  // SC*64
    float* SQ    = SK    + SC * 64;
    float* SKso  = SQ    + SC * 64;
    float* SQsi  = SKso  + SC * 64;
    float* si_g  = SQsi  + SC * 64;     // S*Ll each
    float* rw1_g = si_g  + S * Ll;
    float* rw2_g = rw1_g + S * Ll;
    float* s2_g  = rw2_g + S * Ll;
    float* e_g   = s2_g  + S * Ll;
    float* ecum_g= e_g   + S * Ll;
    float* scomp = ecum_g+ S * Ll;
    float* Tcs   = scomp + S * Ll;      // SC
    float* KVT   = Tcs   + SC;          // SC*4096 f32
    unsigned short* Qb   = (unsigned short*)(KVT + (size_t)SC * 4096);  // SC*4096 bf16 each
    unsigned short* Kb   = Qb   + (size_t)SC * 4096;
    unsigned short* Vt   = Kb   + (size_t)SC * 4096;
    unsigned short* KVpb = Vt   + (size_t)SC * 4096;

    k_stage<<<SC, 256, 0, stream>>>(Q, K, V, Qb, Kb, Vt, SK, SQ);
    k_pass1<<<SC, 256, 0, stream>>>(Qb, Kb, SK, SQ, SKso, SQsi, si_g, rw1_g, rw2_g);
    k_pass2<<<SC, 256, 0, stream>>>(Qb, Kb, SKso, SQsi, si_g, rw1_g, rw2_g, s2_g, e_g, ecum_g, Tcs);
    k_kv<<<SC, 256, 0, stream>>>(Kb, Vt, e_g, ecum_g, Tcs, scomp, KVT);
    k_prefixKV<<<128, 256, 0, stream>>>(KVT, KVpb);
    k_final<<<SC, 256, 0, stream>>>(Qb, Kb, Vt, s2_g, scomp, KVpb, Out);
}

// Round 4
// 103.421 us; speedup vs baseline: 6.7154x; 1.0230x over previous
//
#include <hip/hip_runtime.h>
#include <math.h>

// Problem constants (fixed by reference setup_inputs)
constexpr int Nn = 2, Hh = 8, Ll = 2048, Dd = 64;
constexpr int S  = Nn * Hh;      // 16 sequences
constexpr int C  = 64;           // chunk length
constexpr int NC = Ll / C;       // 32 chunks/seq
constexpr int SC = S * NC;       // 512 chunk-blocks

constexpr int SB  = 72;          // bf16 LDS row stride (144 B rows, 16B-aligned)
constexpr int SRP = 65;          // fp32 score-matrix stride
constexpr int SS8 = 9;           // stride for 8-partial row-sum scratch

#define EPSF 1e-6f
#define FLAG_MAGIC 0x5F3A9D21u

typedef __attribute__((ext_vector_type(8))) short short8;
typedef __attribute__((ext_vector_type(4))) float f32x4;
#define MFMA16(a, b, c) __builtin_amdgcn_mfma_f32_16x16x32_bf16(a, b, c, 0, 0, 0)

__device__ __forceinline__ float rcpf(float x) { return __builtin_amdgcn_rcpf(x); }
__device__ __forceinline__ float sigf(float x) { return rcpf(1.0f + __expf(-x)); }

__device__ __forceinline__ float waveRed(float v) {
#pragma unroll
    for (int off = 32; off > 0; off >>= 1) v += __shfl_xor(v, off, 64);
    return v;
}

__device__ __forceinline__ int gidx(int n, int l, int h, int d) {
    return ((n * Ll + l) * Hh + h) * Dd + d;
}

__device__ __forceinline__ float fc(const float4& v, int u) { return ((const float*)&v)[u]; }

__device__ __forceinline__ unsigned short f2bf(float x) {
    unsigned int u = __float_as_uint(x);
    unsigned int r = (u + 0x7fffu + ((u >> 16) & 1u)) >> 16;   // RNE
    return (unsigned short)r;
}
__device__ __forceinline__ unsigned int pack2(float lo, float hi) {
    return (unsigned int)f2bf(lo) | ((unsigned int)f2bf(hi) << 16);
}
__device__ __forceinline__ float bf2f(unsigned short u) {
    return __uint_as_float(((unsigned int)u) << 16);
}
__device__ __forceinline__ float lo16(unsigned int x) { return __uint_as_float(x << 16); }
__device__ __forceinline__ float hi16(unsigned int x) { return __uint_as_float(x & 0xffff0000u); }
__device__ __forceinline__ void unpack8(const uint4& v, float* o) {
    o[0] = lo16(v.x); o[1] = hi16(v.x); o[2] = lo16(v.y); o[3] = hi16(v.y);
    o[4] = lo16(v.z); o[5] = hi16(v.z); o[6] = lo16(v.w); o[7] = hi16(v.w);
}

// ---- agent-scope coherent publish/read (write-through; NO cache-wide invalidate) ----
__device__ __forceinline__ void pubf(float* p, float v) {
    __hip_atomic_store((unsigned int*)p, __float_as_uint(v),
                       __ATOMIC_RELAXED, __HIP_MEMORY_SCOPE_AGENT);
}
__device__ __forceinline__ float rdf(const float* p) {
    return __uint_as_float(__hip_atomic_load((const unsigned int*)p,
                       __ATOMIC_RELAXED, __HIP_MEMORY_SCOPE_AGENT));
}
// All 256 threads: drain own VMEM, block-barrier, then t==0 sets the flag.
__device__ __forceinline__ void publish_flag(unsigned int* f, int t) {
    asm volatile("s_waitcnt vmcnt(0)" ::: "memory");
    __syncthreads();
    if (t == 0)
        __hip_atomic_store(f, FLAG_MAGIC, __ATOMIC_RELAXED, __HIP_MEMORY_SCOPE_AGENT);
}
// Wave 0 polls predecessor flags (chunks cp<c of sequence s); all waves sync after.
__device__ __forceinline__ void wait_flags(const unsigned int* fbase, int s, int c, int t) {
    if (t < 64) {
        const bool need = (t < c);   // c <= 31 < 64
        for (;;) {
            unsigned int v = need
                ? __hip_atomic_load(&fbase[s * NC + t], __ATOMIC_RELAXED, __HIP_MEMORY_SCOPE_AGENT)
                : FLAG_MAGIC;
            if (__all(v == FLAG_MAGIC)) break;
            __builtin_amdgcn_s_sleep(8);
        }
    }
    __syncthreads();
}

// ============================================================================
// K1 (mega): stage + pass1 + pass2 + kv fused; cross-chunk prefixes via
// decoupled lookback (flags on strictly lower block IDs -> deadlock-free).
// LDS ~52 KB -> 2 blocks/CU -> all 512 blocks co-resident.
// ============================================================================
__global__ __launch_bounds__(256) void k_mega(
        const float* __restrict__ Q, const float* __restrict__ K,
        const float* __restrict__ V,
        unsigned short* __restrict__ Qb, unsigned short* __restrict__ Kb,
        unsigned short* __restrict__ Vt,
        float* __restrict__ SK, float* __restrict__ SQ,
        float* __restrict__ SKso, float* __restrict__ SQsi,
        float* __restrict__ s2_g, float* __restrict__ scomp_g,
        float* __restrict__ Tcs, float* __restrict__ KVT,
        unsigned int* __restrict__ f0, unsigned int* __restrict__ f1,
        unsigned int* __restrict__ f2) {
    __shared__ __align__(16) unsigned short sqB[C * SB];   // sigmoid(Q) rows [i][d]
    __shared__ __align__(16) unsigned short skB[C * SB];   // sigmoid(K) rows [i][d]
    __shared__ __align__(16) unsigned short vsT[C * SB];   // raw V^T; scomp-scaled in place (phase D)
    __shared__ float P[C * SRP];          // stage scratch -> scores -> skT overlay (phase D)
    __shared__ float scrA[C * SS8], scrB[C * SS8];
    __shared__ float colK[C], colQ[C], pk[Dd], pq[Dd];
    __shared__ float lsi[C], lso[C], rw1[C], rw2[C], le[C], ecum[C], lsc[C];
    __shared__ float pcsv;

    const int b = blockIdx.x, s = b / NC, c = b % NC;
    const int n = s / Hh, h = s % Hh, t = threadIdx.x;
    const size_t base = (size_t)b * 4096;

    // ---------------- Phase A: stage (verbatim k_stage arithmetic) ----------------
    {
        int d0 = (4 * t) & 63, ig = t >> 4;
        float psk[4] = {0, 0, 0, 0}, psq[4] = {0, 0, 0, 0};
#pragma unroll
        for (int j = 0; j < 4; j++) {
            int i = ig + 16 * j;
            int id = gidx(n, c * C + i, h, d0);
            float4 q4 = *(const float4*)&Q[id];
            float4 k4 = *(const float4*)&K[id];
            float a0 = sigf(q4.x), a1 = sigf(q4.y), a2 = sigf(q4.z), a3 = sigf(q4.w);
            float b0 = sigf(k4.x), b1 = sigf(k4.y), b2 = sigf(k4.z), b3 = sigf(k4.w);
            uint2 pq2 = make_uint2(pack2(a0, a1), pack2(a2, a3));
            uint2 pk2 = make_uint2(pack2(b0, b1), pack2(b2, b3));
            *(uint2*)&Qb[base + i * 64 + d0] = pq2;      // for k_final
            *(uint2*)&Kb[base + i * 64 + d0] = pk2;      // for k_final
            *(uint2*)&sqB[i * SB + d0] = pq2;            // LDS-resident for all phases
            *(uint2*)&skB[i * SB + d0] = pk2;
            psq[0] += a0; psq[1] += a1; psq[2] += a2; psq[3] += a3;
            psk[0] += b0; psk[1] += b1; psk[2] += b2; psk[3] += b3;
        }
#pragma unroll
        for (int r = 0; r < 4; r++) {
            P[ig * 64 + d0 + r] = psk[r];
            P[1024 + ig * 64 + d0 + r] = psq[r];
        }
        // transposed V: global copy (for k_final) + LDS copy (for phase D)
        int i0 = (t & 15) * 4, dt = (t >> 4) * 4;
        float4 vr[4];
#pragma unroll
        for (int r = 0; r < 4; r++)
            vr[r] = *(const float4*)&V[gidx(n, c * C + i0 + r, h, dt)];
#pragma unroll
        for (int u = 0; u < 4; u++) {
            uint2 wv = make_uint2(pack2(fc(vr[0], u), fc(vr[1], u)),
                                  pack2(fc(vr[2], u), fc(vr[3], u)));
            *(uint2*)&Vt[base + (dt + u) * 64 + i0] = wv;
            *(uint2*)&vsT[(dt + u) * SB + i0] = wv;
        }
    }
    __syncthreads();
    if (t < 64) {           // SK chunk sums -> publish
        float v = 0.f;
        for (int g = 0; g < 16; g++) v += P[g * 64 + t];
        pubf(&SK[b * 64 + t], v);
    } else if (t < 128) {   // SQ chunk sums -> publish
        int d = t - 64; float v = 0.f;
        for (int g = 0; g < 16; g++) v += P[1024 + g * 64 + d];
        pubf(&SQ[b * 64 + d], v);
    }
    publish_flag(&f0[b], t);

    // ---------------- layer-0 lookback ----------------
    wait_flags(f0, s, c, t);

    // ---------------- Phase B: pass1 (verbatim arithmetic) ----------------
    {   // cross-chunk prefix partials (4 groups), coherent reads
        int d = t & 63, g = t >> 6;
        float pa = 0.f, pb = 0.f;
        for (int cp = g; cp < c; cp += 4) {
            pa += rdf(&SK[(s * NC + cp) * 64 + d]);
            pb += rdf(&SQ[(s * NC + cp) * 64 + d]);
        }
        P[2048 + g * 64 + d] = pa;
        P[2304 + g * 64 + d] = pb;
    }
#pragma unroll
    for (int j = 0; j < 2; j++) {   // per-row 8-partial sums from LDS tiles (same bits)
        int flat = 8 * t + 2048 * j, i = flat >> 6, d0 = flat & 63;
        uint4 xq = *(const uint4*)&sqB[i * SB + d0];
        uint4 xk = *(const uint4*)&skB[i * SB + d0];
        float qa[8], ka[8];
        unpack8(xq, qa); unpack8(xk, ka);
        float sq = 0.f, sk = 0.f;
#pragma unroll
        for (int u = 0; u < 8; u++) { sq += qa[u]; sk += ka[u]; }
        scrB[i * SS8 + (d0 >> 3)] = sq;
        scrA[i * SS8 + (d0 >> 3)] = sk;
    }
    __syncthreads();
    if (t < 64) {
        float v = 0.f;
#pragma unroll
        for (int u = 0; u < 8; u++) v += scrA[t * SS8 + u];
        colK[t] = v;
    } else if (t < 128) {
        int i = t - 64; float v = 0.f;
#pragma unroll
        for (int u = 0; u < 8; u++) v += scrB[i * SS8 + u];
        colQ[i] = v;
    } else if (t < 192) {
        int d = t - 128;
        pk[d] = P[2048 + d] + P[2112 + d] + P[2176 + d] + P[2240 + d];
    } else {
        int d = t - 192;
        pq[d] = P[2304 + d] + P[2368 + d] + P[2432 + d] + P[2496 + d];
    }
    __syncthreads();

    {   // MFMA: P = sq · sk^T
        int w = t >> 6, lane = t & 63, m = lane & 15, q = lane >> 4;
        f32x4 acc[4] = {{0,0,0,0},{0,0,0,0},{0,0,0,0},{0,0,0,0}};
#pragma unroll
        for (int kk = 0; kk < 64; kk += 32) {
            short8 a = *(const short8*)&sqB[(16 * w + m) * SB + kk + q * 8];
#pragma unroll
            for (int J = 0; J < 4; J++) {
                short8 bb = *(const short8*)&skB[(16 * J + m) * SB + kk + q * 8];
                acc[J] = MFMA16(a, bb, acc[J]);
            }
        }
#pragma unroll
        for (int J = 0; J < 4; J++)
#pragma unroll
            for (int r = 0; r < 4; r++)
                P[(16 * w + 4 * q + r) * SRP + 16 * J + m] = acc[J][r];
    }
    __syncthreads();

    {   // si/so: 4 lanes per row
        int i = t >> 2, g = t & 3, l = c * C + i;
        float r1 = 0.f, r2 = 0.f;
        for (int jj = g; jj <= i; jj += 4) {
            r1 += P[i * SRP + jj] + EPSF * colK[jj];
            r2 += P[jj * SRP + i] + EPSF * colQ[jj];
        }
        float b1 = 0.f, b2 = 0.f;
#pragma unroll
        for (int u = 0; u < 16; u++) {
            int d = g * 16 + u;
            b1 += (bf2f(sqB[i * SB + d]) + EPSF) * (pk[d] + EPSF);
            b2 += (bf2f(skB[i * SB + d]) + EPSF) * (pq[d] + EPSF);
        }
        r1 += __shfl_xor(r1, 1, 64); r1 += __shfl_xor(r1, 2, 64);
        r2 += __shfl_xor(r2, 1, 64); r2 += __shfl_xor(r2, 2, 64);
        b1 += __shfl_xor(b1, 1, 64); b1 += __shfl_xor(b1, 2, 64);
        b2 += __shfl_xor(b2, 1, 64); b2 += __shfl_xor(b2, 2, 64);
        if (g == 0) {
            float nf = (float)(l + 1);
            lsi[i] = nf * rcpf(b1 + r1);
            lso[i] = nf * rcpf(b2 + r2);
        }
    }
    __syncthreads();

    {   // rw1/rw2 -> LDS (consumed by phase C)
        int i = t >> 2, g = t & 3;
        float a1 = 0.f, a2 = 0.f;
        for (int jj = g; jj <= i; jj += 4) {
            a1 += lso[jj] * (P[i * SRP + jj] + EPSF * colK[jj]);
            a2 += lsi[jj] * (P[jj * SRP + i] + EPSF * colQ[jj]);
        }
        a1 += __shfl_xor(a1, 1, 64); a1 += __shfl_xor(a1, 2, 64);
        a2 += __shfl_xor(a2, 1, 64); a2 += __shfl_xor(a2, 2, 64);
        if (g == 0) { rw1[i] = a1; rw2[i] = a2; }
    }
    {   // SKso/SQsi -> publish
        int d = t >> 2, g = t & 3;
        float v1 = 0.f, v2 = 0.f;
#pragma unroll
        for (int u = 0; u < 16; u++) {
            int i = g * 16 + u;
            v1 += bf2f(skB[i * SB + d]) * lso[i];
            v2 += bf2f(sqB[i * SB + d]) * lsi[i];
        }
        v1 += __shfl_xor(v1, 1, 64); v1 += __shfl_xor(v1, 2, 64);
        v2 += __shfl_xor(v2, 1, 64); v2 += __shfl_xor(v2, 2, 64);
        if (g == 0) {
            pubf(&SKso[b * 64 + d], v1);
            pubf(&SQsi[b * 64 + d], v2);
        }
    }
    publish_flag(&f1[b], t);

    // ---------------- layer-1 lookback ----------------
    wait_flags(f1, s, c, t);

    // ---------------- Phase C: pass2 (verbatim arithmetic) ----------------
    {
        int d = t & 63, g = t >> 6;
        float pa = 0.f, pb = 0.f;
        for (int cp = g; cp < c; cp += 4) {
            pa += rdf(&SKso[(s * NC + cp) * 64 + d]);
            pb += rdf(&SQsi[(s * NC + cp) * 64 + d]);
        }
        scrA[g * 64 + d] = pa;
        scrA[256 + g * 64 + d] = pb;
    }
    __syncthreads();
    if (t < 64) pk[t] = scrA[t] + scrA[64 + t] + scrA[128 + t] + scrA[192 + t];
    else if (t < 128) {
        int d = t - 64;
        pq[d] = scrA[256 + d] + scrA[320 + d] + scrA[384 + d] + scrA[448 + d];
    }
    __syncthreads();
    {
        int i = t >> 2, g = t & 3, l = c * C + i;
        float b1 = 0.f, b2 = 0.f;
#pragma unroll
        for (int j = 0; j < 2; j++) {
            uint4 xq = *(const uint4*)&sqB[i * SB + g * 16 + 8 * j];
            uint4 xk = *(const uint4*)&skB[i * SB + g * 16 + 8 * j];
            float qa[8], ka[8];
            unpack8(xq, qa); unpack8(xk, ka);
            int d = g * 16 + 8 * j;
#pragma unroll
            for (int u = 0; u < 8; u++) {
                b1 += (qa[u] + EPSF) * (pk[d + u] + EPSF);
                b2 += (ka[u] + EPSF) * (pq[d + u] + EPSF);
            }
        }
        b1 += __shfl_xor(b1, 1, 64); b1 += __shfl_xor(b1, 2, 64);
        b2 += __shfl_xor(b2, 1, 64); b2 += __shfl_xor(b2, 2, 64);
        if (g == 0) {
            float nf = (float)(l + 1);
            float cs  = (b1 + rw1[i]) * rcpf(nf);
            float csr = (b2 + rw2[i]) * rcpf(nf);
            csr = fminf(fmaxf(csr, -1.f), 1.f);
            float e = __expf(csr);
            float sal = sigf(cs);
            s2_g[s * Ll + l] = lsi[i] * rcpf(nf) * sal;   // normal store (k_final input)
            le[i] = e;
        }
    }
    __syncthreads();
    if (t < 64) {           // inclusive chunk-local scan of e; Tcs = chunk total
        float run = le[t];
#pragma unroll
        for (int off = 1; off < 64; off <<= 1) {
            float o = __shfl_up(run, off, 64);
            if (t >= off) run += o;
        }
        ecum[t] = run;
        if (t == 63) pubf(&Tcs[b], run);
    }
    publish_flag(&f2[b], t);

    // ---------------- layer-2 lookback ----------------
    wait_flags(f2, s, c, t);

    // ---------------- Phase D: kv (verbatim arithmetic) ----------------
    if (t < 64) {
        float v = (t < c) ? rdf(&Tcs[s * NC + t]) : 0.f;
        v = waveRed(v);
        if (t == 0) pcsv = v;
    }
    __syncthreads();
    if (t < 64) {
        int l = c * C + t;
        float ls = le[t] * rcpf(pcsv + ecum[t]) * (float)(l + 1);
        lsc[t] = ls;
        scomp_g[s * Ll + l] = ls;       // normal store (k_final input)
    }
    __syncthreads();

    unsigned short* skT = (unsigned short*)P;   // P free now; overlay K^T [d][i]
#pragma unroll
    for (int j = 0; j < 2; j++) {   // scomp-scale vsT in place
        int flat = 8 * t + 2048 * j, dR = flat >> 6, i0 = flat & 63;
        uint4 vv = *(const uint4*)&vsT[dR * SB + i0];
        float x[8];
        unpack8(vv, x);
#pragma unroll
        for (int u = 0; u < 8; u++) x[u] *= lsc[i0 + u];
        uint4 o;
        o.x = pack2(x[0], x[1]); o.y = pack2(x[2], x[3]);
        o.z = pack2(x[4], x[5]); o.w = pack2(x[6], x[7]);
        *(uint4*)&vsT[dR * SB + i0] = o;
    }
    {   // skB -> skT bit-shuffle transpose
        int i0 = (t & 15) * 4, dt = (t >> 4) * 4;
        uint2 kr[4];
#pragma unroll
        for (int r = 0; r < 4; r++) kr[r] = *(const uint2*)&skB[(i0 + r) * SB + dt];
#pragma unroll
        for (int u = 0; u < 4; u++) {
            unsigned int e0 = (u < 2 ? kr[0].x : kr[0].y), e1 = (u < 2 ? kr[1].x : kr[1].y);
            unsigned int e2 = (u < 2 ? kr[2].x : kr[2].y), e3 = (u < 2 ? kr[3].x : kr[3].y);
            int sh = (u & 1) * 16;
            unsigned int lo = ((e0 >> sh) & 0xffffu) | (((e1 >> sh) & 0xffffu) << 16);
            unsigned int hi = ((e2 >> sh) & 0xffffu) | (((e3 >> sh) & 0xffffu) << 16);
            *(uint2*)&skT[(dt + u) * SB + i0] = make_uint2(lo, hi);
        }
    }
    __syncthreads();

    {   // MFMA: KVT[m][d] = sum_i vsT[m][i] * skT[d][i]  (normal stores; kernel-boundary coherence)
        int w = t >> 6, lane = t & 63, m = lane & 15, q = lane >> 4;
        f32x4 acc[4] = {{0,0,0,0},{0,0,0,0},{0,0,0,0},{0,0,0,0}};
#pragma unroll
        for (int kk = 0; kk < 64; kk += 32) {
            short8 a = *(const short8*)&vsT[(16 * w + m) * SB + kk + q * 8];
#pragma unroll
            for (int J = 0; J < 4; J++) {
                short8 bb = *(const short8*)&skT[(16 * J + m) * SB + kk + q * 8];
                acc[J] = MFMA16(a, bb, acc[J]);
            }
        }
#pragma unroll
        for (int J = 0; J < 4; J++)
#pragma unroll
            for (int r = 0; r < 4; r++)
                KVT[(size_t)b * 4096 + (16 * w + 4 * q + r) * 64 + 16 * J + m] = acc[J][r];
    }
}

// K2: exclusive chunk-prefix of KVT; f32 accumulation (same order), bf16 output.
__global__ __launch_bounds__(256) void k_prefixKV(const float* __restrict__ KVT,
                                                  unsigned short* __restrict__ KVpb) {
    int bx = blockIdx.x, s = bx >> 3, sub = bx & 7;
    int e0 = sub * 512 + 2 * threadIdx.x;
    float2 x[NC];
#pragma unroll
    for (int cp = 0; cp < NC; cp++)
        x[cp] = *(const float2*)&KVT[(size_t)(s * NC + cp) * 4096 + e0];
    float r0 = 0.f, r1 = 0.f;
#pragma unroll
    for (int cp = 0; cp < NC; cp++) {
        *(unsigned int*)&KVpb[(size_t)(s * NC + cp) * 4096 + e0] = pack2(r0, r1);
        r0 += x[cp].x; r1 += x[cp].y;
    }
}

// K3: final — P recomputed via MFMA; prefix-KV read as bf16 rows (KVpb).
__global__ __launch_bounds__(256) void k_final(const unsigned short* __restrict__ Qb,
                                               const unsigned short* __restrict__ Kb,
                                               const unsigned short* __restrict__ Vt,
                                               const float* __restrict__ s2_g,
                                               const float* __restrict__ scomp_g,
                                               const unsigned short* __restrict__ KVpb,
                                               float* __restrict__ Out) {
    __shared__ __align__(16) unsigned short sqB[C * SB];    // [i][d]
    __shared__ __align__(16) unsigned short skB[C * SB];    // sk rows; later kvB [m][d]
    __shared__ __align__(16) unsigned short vsT[C * SB];    // [m][j] raw v
    __shared__ __align__(16) unsigned short stB[C * SB];    // [i][j] masked P*scomp
    __shared__ float lsc[C], s2l[C];
    int b = blockIdx.x, s = b / NC, c = b % NC;
    int n = s / Hh, h = s % Hh, t = threadIdx.x;
    int w = t >> 6, lane = t & 63, mf = lane & 15, qq = lane >> 4;
    int I0 = 16 * w;

    if (t < 64) lsc[t] = scomp_g[s * Ll + c * C + t];
    else if (t < 128) s2l[t - 64] = s2_g[s * Ll + c * C + (t - 64)];

    size_t base = (size_t)b * 4096;
    // early prefix-KV loads (hidden behind staging + P-MFMA)
    uint4 kvp[2];
#pragma unroll
    for (int j = 0; j < 2; j++)
        kvp[j] = *(const uint4*)&KVpb[base + 8 * t + 2048 * j];

#pragma unroll
    for (int j = 0; j < 2; j++) {
        int flat = 8 * t + 2048 * j, i = flat >> 6, d0 = flat & 63;
        *(uint4*)&sqB[i * SB + d0] = *(const uint4*)&Qb[base + flat];
        *(uint4*)&skB[i * SB + d0] = *(const uint4*)&Kb[base + flat];
        *(uint4*)&vsT[i * SB + d0] = *(const uint4*)&Vt[base + flat];
    }
    __syncthreads();

    // P recompute: wave w owns row-block I0; mask+scale -> stB
    {
        f32x4 acc[4] = {{0,0,0,0},{0,0,0,0},{0,0,0,0},{0,0,0,0}};
#pragma unroll
        for (int kk = 0; kk < 64; kk += 32) {
            short8 a = *(const short8*)&sqB[(I0 + mf) * SB + kk + qq * 8];
#pragma unroll
            for (int J = 0; J < 4; J++) {
                short8 bb2 = *(const short8*)&skB[(16 * J + mf) * SB + kk + qq * 8];
                acc[J] = MFMA16(a, bb2, acc[J]);
            }
        }
#pragma unroll
        for (int J = 0; J < 4; J++)
#pragma unroll
            for (int r = 0; r < 4; r++) {
                int i = I0 + 4 * qq + r, jj = 16 * J + mf;
                float v = (jj <= i) ? acc[J][r] * lsc[jj] : 0.f;
                stB[i * SB + jj] = f2bf(v);
            }
    }
    __syncthreads();   // skB reads done; stB ready

    // overlay kvB (= exclusive-prefix KV rows [m][d], already bf16) onto skB
#pragma unroll
    for (int j = 0; j < 2; j++) {
        int flat = 8 * t + 2048 * j, i = flat >> 6, d0 = flat & 63;
        *(uint4*)&skB[i * SB + d0] = kvp[j];
    }
    __syncthreads();

    f32x4 acc[4] = {{0,0,0,0},{0,0,0,0},{0,0,0,0},{0,0,0,0}};
#pragma unroll
    for (int kk = 0; kk < 64; kk += 32) {   // mm1: sq · KVp ; mm2: stB · v
        short8 a1 = *(const short8*)&sqB[(I0 + mf) * SB + kk + qq * 8];
        short8 a2 = *(const short8*)&stB[(I0 + mf) * SB + kk + qq * 8];
#pragma unroll
        for (int J = 0; J < 4; J++) {
            short8 b1 = *(const short8*)&skB[(16 * J + mf) * SB + kk + qq * 8];
            acc[J] = MFMA16(a1, b1, acc[J]);
            short8 b2 = *(const short8*)&vsT[(16 * J + mf) * SB + kk + qq * 8];
            acc[J] = MFMA16(a2, b2, acc[J]);
        }
    }
#pragma unroll
    for (int J = 0; J < 4; J++)
#pragma unroll
        for (int r = 0; r < 4; r++) {
            int io = I0 + 4 * qq + r;
            Out[gidx(n, c * C + io, h, 16 * J + mf)] = acc[J][r] * s2l[io];
        }
}

extern "C" void kernel_launch(void* const* d_in, const int* in_sizes, int n_in,
                              void* d_out, int out_size, void* d_ws, size_t ws_size,
                              hipStream_t stream) {
    const float* Q = (const float*)d_in[0];
    const float* K = (const float*)d_in[1];
    const float* V = (const float*)d_in[2];
    float* Out = (float*)d_out;

    float* ws    = (float*)d_ws;
    float* SK    = ws;                  // SC*64
    float* SQ    = SK    + SC * 64;
    float* SKso  = SQ    + SC * 64;
    float* SQsi  = SKso  + SC * 64;
    float* s2_g  = SQsi  + SC * 64;     // S*Ll
    float* scomp = s2_g  + S * Ll;      // S*Ll
    float* Tcs   = scomp + S * Ll;      // SC
    float* KVT   = Tcs   + SC;          // SC*4096 f32
    unsigned short* Qb   = (unsigned short*)(KVT + (size_t)SC * 4096);  // SC*4096 bf16 each
    unsigned short* Kb   = Qb   + (size_t)SC * 4096;
    unsigned short* Vt   = Kb   + (size_t)SC * 4096;
    unsigned short* KVpb = Vt   + (size_t)SC * 4096;
    unsigned int*   f0   = (unsigned int*)(KVpb + (size_t)SC * 4096);   // SC each
    unsigned int*   f1   = f0 + SC;
    unsigned int*   f2   = f1 + SC;

    k_mega<<<SC, 256, 0, stream>>>(Q, K, V, Qb, Kb, Vt, SK, SQ, SKso, SQsi,
                                   s2_g, scomp, Tcs, KVT, f0, f1, f2);
    k_prefixKV<<<128, 256, 0, stream>>>(KVT, KVpb);
    k_final<<<SC, 256, 0, stream>>>(Qb, Kb, Vt, s2_g, scomp, KVpb, Out);
}

// Round 5
// 99.231 us; speedup vs baseline: 6.9990x; 1.0422x over previous
//
#include <hip/hip_runtime.h>
#include <math.h>

// Problem constants (fixed by reference setup_inputs)
constexpr int Nn = 2, Hh = 8, Ll = 2048, Dd = 64;
constexpr int S  = Nn * Hh;      // 16 sequences
constexpr int C  = 64;           // chunk length
constexpr int NC = Ll / C;       // 32 chunks/seq
constexpr int SC = S * NC;       // 512 chunk-blocks

constexpr int SB  = 72;          // bf16 LDS row stride (144 B rows, 16B-aligned)
constexpr int SRP = 65;          // fp32 score-matrix stride
constexpr int SS8 = 9;           // stride for 8-partial row-sum scratch

#define EPSF 1e-6f
#define FLAG_MAGIC 0x5F3A9D21u

typedef __attribute__((ext_vector_type(8))) short short8;
typedef __attribute__((ext_vector_type(4))) float f32x4;
#define MFMA16(a, b, c) __builtin_amdgcn_mfma_f32_16x16x32_bf16(a, b, c, 0, 0, 0)

__device__ __forceinline__ float rcpf(float x) { return __builtin_amdgcn_rcpf(x); }
__device__ __forceinline__ float sigf(float x) { return rcpf(1.0f + __expf(-x)); }

__device__ __forceinline__ float waveRed(float v) {
#pragma unroll
    for (int off = 32; off > 0; off >>= 1) v += __shfl_xor(v, off, 64);
    return v;
}

__device__ __forceinline__ int gidx(int n, int l, int h, int d) {
    return ((n * Ll + l) * Hh + h) * Dd + d;
}

__device__ __forceinline__ float fc(const float4& v, int u) { return ((const float*)&v)[u]; }

__device__ __forceinline__ unsigned short f2bf(float x) {
    unsigned int u = __float_as_uint(x);
    unsigned int r = (u + 0x7fffu + ((u >> 16) & 1u)) >> 16;   // RNE
    return (unsigned short)r;
}
__device__ __forceinline__ unsigned int pack2(float lo, float hi) {
    return (unsigned int)f2bf(lo) | ((unsigned int)f2bf(hi) << 16);
}
__device__ __forceinline__ float bf2f(unsigned short u) {
    return __uint_as_float(((unsigned int)u) << 16);
}
__device__ __forceinline__ float lo16(unsigned int x) { return __uint_as_float(x << 16); }
__device__ __forceinline__ float hi16(unsigned int x) { return __uint_as_float(x & 0xffff0000u); }
__device__ __forceinline__ void unpack8(const uint4& v, float* o) {
    o[0] = lo16(v.x); o[1] = hi16(v.x); o[2] = lo16(v.y); o[3] = hi16(v.y);
    o[4] = lo16(v.z); o[5] = hi16(v.z); o[6] = lo16(v.w); o[7] = hi16(v.w);
}

// ---- agent-scope coherent publish/read (write-through to LLC; no cache-wide inv) ----
__device__ __forceinline__ void pubf(float* p, float v) {
    __hip_atomic_store((unsigned int*)p, __float_as_uint(v),
                       __ATOMIC_RELAXED, __HIP_MEMORY_SCOPE_AGENT);
}
__device__ __forceinline__ float rdf(const float* p) {
    return __uint_as_float(__hip_atomic_load((const unsigned int*)p,
                       __ATOMIC_RELAXED, __HIP_MEMORY_SCOPE_AGENT));
}
__device__ __forceinline__ void pubu(unsigned int* p, unsigned int v) {
    __hip_atomic_store(p, v, __ATOMIC_RELAXED, __HIP_MEMORY_SCOPE_AGENT);
}
__device__ __forceinline__ unsigned long long rd64(const void* p) {
    return __hip_atomic_load((const unsigned long long*)p,
                             __ATOMIC_RELAXED, __HIP_MEMORY_SCOPE_AGENT);
}
// All 256 threads: drain own VMEM, block-barrier, then t==0 sets the flag.
__device__ __forceinline__ void publish_flag(unsigned int* f, int t) {
    asm volatile("s_waitcnt vmcnt(0)" ::: "memory");
    __syncthreads();
    if (t == 0)
        __hip_atomic_store(f, FLAG_MAGIC, __ATOMIC_RELAXED, __HIP_MEMORY_SCOPE_AGENT);
}
// Wave 0 polls n flags at f[0..n); all waves sync after. n <= 64.
__device__ __forceinline__ void wait_n(const unsigned int* f, int n, int t) {
    if (t < 64) {
        const bool need = (t < n);
        for (;;) {
            unsigned int v = need
                ? __hip_atomic_load(&f[t], __ATOMIC_RELAXED, __HIP_MEMORY_SCOPE_AGENT)
                : FLAG_MAGIC;
            if (__all(v == FLAG_MAGIC)) break;
            __builtin_amdgcn_s_sleep(8);
        }
    }
    __syncthreads();
}

// ============================================================================
// Single persistent kernel. Block b owns chunk (s=b/NC, c=b%NC) for all phases;
// blocks b<128 additionally perform the KVT sequence-prefix (phase E).
// Cross-block deps via decoupled-lookback flags + agent-scope (LLC) atomics.
// LDS ~61.5 KB, VGPR capped by __launch_bounds__(256,2) -> 2 blocks/CU ->
// all 512 blocks co-resident (required: phase E waits on higher block IDs).
// ============================================================================
__global__ __launch_bounds__(256, 2) void k_all(
        const float* __restrict__ Q, const float* __restrict__ K,
        const float* __restrict__ V,
        float* __restrict__ SK, float* __restrict__ SQ,
        float* __restrict__ SKso, float* __restrict__ SQsi,
        float* __restrict__ Tcs, float* __restrict__ KVT,
        unsigned short* __restrict__ KVpb, float* __restrict__ Out,
        unsigned int* __restrict__ f0, unsigned int* __restrict__ f1,
        unsigned int* __restrict__ f2, unsigned int* __restrict__ f3,
        unsigned int* __restrict__ f4) {
    __shared__ __align__(16) unsigned short sqB[C * SB];   // sigmoid(Q) rows [i][d]   (A..F)
    __shared__ __align__(16) unsigned short skB[C * SB];   // sigmoid(K) rows; F: KV-prefix rows
    __shared__ __align__(16) unsigned short vsT[C * SB];   // raw V^T [m][i]           (A..F)
    __shared__ __align__(16) unsigned short stB[C * SB];   // D..F: masked P*scomp bf16
    __shared__ __align__(16) float Pun[4608];              // A: scratch; B..D: P scores; D: skT+vsV
    __shared__ float scrA[C * SS8], scrB[C * SS8];
    __shared__ float colK[C], colQ[C], pk[Dd], pq[Dd];
    __shared__ float lsi[C], lso[C], rw1[C], rw2[C], le[C], ecum[C], lsc[C], s2l[C];
    __shared__ float pcsv;

    const int b = blockIdx.x, s = b / NC, c = b % NC;
    const int n = s / Hh, h = s % Hh, t = threadIdx.x;
    const int w = t >> 6, lane = t & 63, mf = lane & 15, qq = lane >> 4;
    const int I0 = 16 * w;
    float* P = Pun;

    // ---------------- Phase A: stage (sigmoid once; LDS-resident tiles) ----------------
    {
        int d0 = (4 * t) & 63, ig = t >> 4;
        float psk[4] = {0, 0, 0, 0}, psq[4] = {0, 0, 0, 0};
#pragma unroll
        for (int j = 0; j < 4; j++) {
            int i = ig + 16 * j;
            int id = gidx(n, c * C + i, h, d0);
            float4 q4 = *(const float4*)&Q[id];
            float4 k4 = *(const float4*)&K[id];
            float a0 = sigf(q4.x), a1 = sigf(q4.y), a2 = sigf(q4.z), a3 = sigf(q4.w);
            float b0 = sigf(k4.x), b1 = sigf(k4.y), b2 = sigf(k4.z), b3 = sigf(k4.w);
            *(uint2*)&sqB[i * SB + d0] = make_uint2(pack2(a0, a1), pack2(a2, a3));
            *(uint2*)&skB[i * SB + d0] = make_uint2(pack2(b0, b1), pack2(b2, b3));
            psq[0] += a0; psq[1] += a1; psq[2] += a2; psq[3] += a3;
            psk[0] += b0; psk[1] += b1; psk[2] += b2; psk[3] += b3;
        }
#pragma unroll
        for (int r = 0; r < 4; r++) {
            P[ig * 64 + d0 + r] = psk[r];
            P[1024 + ig * 64 + d0 + r] = psq[r];
        }
        // raw V^T [m][i] into LDS only
        int i0 = (t & 15) * 4, dt = (t >> 4) * 4;
        float4 vr[4];
#pragma unroll
        for (int r = 0; r < 4; r++)
            vr[r] = *(const float4*)&V[gidx(n, c * C + i0 + r, h, dt)];
#pragma unroll
        for (int u = 0; u < 4; u++)
            *(uint2*)&vsT[(dt + u) * SB + i0] = make_uint2(
                pack2(fc(vr[0], u), fc(vr[1], u)), pack2(fc(vr[2], u), fc(vr[3], u)));
    }
    __syncthreads();
    if (t < 64) {
        float v = 0.f;
#pragma unroll
        for (int g = 0; g < 16; g++) v += P[g * 64 + t];
        pubf(&SK[b * 64 + t], v);
    } else if (t < 128) {
        int d = t - 64; float v = 0.f;
#pragma unroll
        for (int g = 0; g < 16; g++) v += P[1024 + g * 64 + d];
        pubf(&SQ[b * 64 + d], v);
    }
    publish_flag(&f0[b], t);

    // ---------------- layer-0 lookback ----------------
    wait_n(&f0[s * NC], c, t);

    // ---------------- Phase B: P MFMA, si/so, rw1/rw2, SKso/SQsi ----------------
    {   // cross-chunk prefix partials: fixed-trip masked (values cp>=c discarded via +0.0f)
        int d = t & 63, g = t >> 6;
        float pa = 0.f, pb = 0.f;
#pragma unroll
        for (int u = 0; u < 8; u++) {
            int cp = g + 4 * u;
            float va = rdf(&SK[(s * NC + cp) * 64 + d]);
            float vb = rdf(&SQ[(s * NC + cp) * 64 + d]);
            pa += (cp < c) ? va : 0.f;
            pb += (cp < c) ? vb : 0.f;
        }
        P[2048 + g * 64 + d] = pa;
        P[2304 + g * 64 + d] = pb;
    }
#pragma unroll
    for (int j = 0; j < 2; j++) {   // per-row 8-partial sums from LDS tiles (same bits)
        int flat = 8 * t + 2048 * j, i = flat >> 6, d0 = flat & 63;
        uint4 xq = *(const uint4*)&sqB[i * SB + d0];
        uint4 xk = *(const uint4*)&skB[i * SB + d0];
        float qa[8], ka[8];
        unpack8(xq, qa); unpack8(xk, ka);
        float sq = 0.f, sk = 0.f;
#pragma unroll
        for (int u = 0; u < 8; u++) { sq += qa[u]; sk += ka[u]; }
        scrB[i * SS8 + (d0 >> 3)] = sq;
        scrA[i * SS8 + (d0 >> 3)] = sk;
    }
    __syncthreads();
    if (t < 64) {
        float v = 0.f;
#pragma unroll
        for (int u = 0; u < 8; u++) v += scrA[t * SS8 + u];
        colK[t] = v;
    } else if (t < 128) {
        int i = t - 64; float v = 0.f;
#pragma unroll
        for (int u = 0; u < 8; u++) v += scrB[i * SS8 + u];
        colQ[i] = v;
    } else if (t < 192) {
        int d = t - 128;
        pk[d] = P[2048 + d] + P[2112 + d] + P[2176 + d] + P[2240 + d];
    } else {
        int d = t - 192;
        pq[d] = P[2304 + d] + P[2368 + d] + P[2432 + d] + P[2496 + d];
    }
    __syncthreads();

    {   // MFMA: P = sq · sk^T (kept in LDS through phase D)
        f32x4 acc[4] = {{0,0,0,0},{0,0,0,0},{0,0,0,0},{0,0,0,0}};
#pragma unroll
        for (int kk = 0; kk < 64; kk += 32) {
            short8 a = *(const short8*)&sqB[(I0 + mf) * SB + kk + qq * 8];
#pragma unroll
            for (int J = 0; J < 4; J++) {
                short8 bb = *(const short8*)&skB[(16 * J + mf) * SB + kk + qq * 8];
                acc[J] = MFMA16(a, bb, acc[J]);
            }
        }
#pragma unroll
        for (int J = 0; J < 4; J++)
#pragma unroll
            for (int r = 0; r < 4; r++)
                P[(I0 + 4 * qq + r) * SRP + 16 * J + mf] = acc[J][r];
    }
    __syncthreads();

    {   // si/so: fixed-trip masked triangular scan (P > 0 -> +0.0f identity, bit-exact)
        int i = t >> 2, g = t & 3, l = c * C + i;
        float r1 = 0.f, r2 = 0.f;
#pragma unroll
        for (int u = 0; u < 16; u++) {
            int jj = g + 4 * u;
            float t1 = P[i * SRP + jj] + EPSF * colK[jj];
            float t2 = P[jj * SRP + i] + EPSF * colQ[jj];
            bool ok = (jj <= i);
            r1 += ok ? t1 : 0.f;
            r2 += ok ? t2 : 0.f;
        }
        float b1 = 0.f, b2 = 0.f;
#pragma unroll
        for (int u = 0; u < 16; u++) {
            int d = g * 16 + u;
            b1 += (bf2f(sqB[i * SB + d]) + EPSF) * (pk[d] + EPSF);
            b2 += (bf2f(skB[i * SB + d]) + EPSF) * (pq[d] + EPSF);
        }
        r1 += __shfl_xor(r1, 1, 64); r1 += __shfl_xor(r1, 2, 64);
        r2 += __shfl_xor(r2, 1, 64); r2 += __shfl_xor(r2, 2, 64);
        b1 += __shfl_xor(b1, 1, 64); b1 += __shfl_xor(b1, 2, 64);
        b2 += __shfl_xor(b2, 1, 64); b2 += __shfl_xor(b2, 2, 64);
        if (g == 0) {
            float nf = (float)(l + 1);
            lsi[i] = nf * rcpf(b1 + r1);
            lso[i] = nf * rcpf(b2 + r2);
        }
    }
    __syncthreads();

    {   // rw1/rw2: fixed-trip masked
        int i = t >> 2, g = t & 3;
        float a1 = 0.f, a2 = 0.f;
#pragma unroll
        for (int u = 0; u < 16; u++) {
            int jj = g + 4 * u;
            float t1 = lso[jj] * (P[i * SRP + jj] + EPSF * colK[jj]);
            float t2 = lsi[jj] * (P[jj * SRP + i] + EPSF * colQ[jj]);
            bool ok = (jj <= i);
            a1 += ok ? t1 : 0.f;
            a2 += ok ? t2 : 0.f;
        }
        a1 += __shfl_xor(a1, 1, 64); a1 += __shfl_xor(a1, 2, 64);
        a2 += __shfl_xor(a2, 1, 64); a2 += __shfl_xor(a2, 2, 64);
        if (g == 0) { rw1[i] = a1; rw2[i] = a2; }
    }
    {   // SKso/SQsi -> publish
        int d = t >> 2, g = t & 3;
        float v1 = 0.f, v2 = 0.f;
#pragma unroll
        for (int u = 0; u < 16; u++) {
            int i = g * 16 + u;
            v1 += bf2f(skB[i * SB + d]) * lso[i];
            v2 += bf2f(sqB[i * SB + d]) * lsi[i];
        }
        v1 += __shfl_xor(v1, 1, 64); v1 += __shfl_xor(v1, 2, 64);
        v2 += __shfl_xor(v2, 1, 64); v2 += __shfl_xor(v2, 2, 64);
        if (g == 0) {
            pubf(&SKso[b * 64 + d], v1);
            pubf(&SQsi[b * 64 + d], v2);
        }
    }
    publish_flag(&f1[b], t);

    // ---------------- layer-1 lookback ----------------
    wait_n(&f1[s * NC], c, t);

    // ---------------- Phase C: cs/csr, e, s2, ecum, Tcs ----------------
    {
        int d = t & 63, g = t >> 6;
        float pa = 0.f, pb = 0.f;
#pragma unroll
        for (int u = 0; u < 8; u++) {
            int cp = g + 4 * u;
            float va = rdf(&SKso[(s * NC + cp) * 64 + d]);
            float vb = rdf(&SQsi[(s * NC + cp) * 64 + d]);
            pa += (cp < c) ? va : 0.f;
            pb += (cp < c) ? vb : 0.f;
        }
        scrA[g * 64 + d] = pa;
        scrA[256 + g * 64 + d] = pb;
    }
    __syncthreads();
    if (t < 64) pk[t] = scrA[t] + scrA[64 + t] + scrA[128 + t] + scrA[192 + t];
    else if (t < 128) {
        int d = t - 64;
        pq[d] = scrA[256 + d] + scrA[320 + d] + scrA[384 + d] + scrA[448 + d];
    }
    __syncthreads();
    {
        int i = t >> 2, g = t & 3, l = c * C + i;
        float b1 = 0.f, b2 = 0.f;
#pragma unroll
        for (int j = 0; j < 2; j++) {
            uint4 xq = *(const uint4*)&sqB[i * SB + g * 16 + 8 * j];
            uint4 xk = *(const uint4*)&skB[i * SB + g * 16 + 8 * j];
            float qa[8], ka[8];
            unpack8(xq, qa); unpack8(xk, ka);
            int d = g * 16 + 8 * j;
#pragma unroll
            for (int u = 0; u < 8; u++) {
                b1 += (qa[u] + EPSF) * (pk[d + u] + EPSF);
                b2 += (ka[u] + EPSF) * (pq[d + u] + EPSF);
            }
        }
        b1 += __shfl_xor(b1, 1, 64); b1 += __shfl_xor(b1, 2, 64);
        b2 += __shfl_xor(b2, 1, 64); b2 += __shfl_xor(b2, 2, 64);
        if (g == 0) {
            float nf = (float)(l + 1);
            float cs  = (b1 + rw1[i]) * rcpf(nf);
            float csr = (b2 + rw2[i]) * rcpf(nf);
            csr = fminf(fmaxf(csr, -1.f), 1.f);
            float e = __expf(csr);
            float sal = sigf(cs);
            s2l[i] = lsi[i] * rcpf(nf) * sal;
            le[i] = e;
        }
    }
    __syncthreads();
    if (t < 64) {           // inclusive chunk-local scan of e; Tcs = chunk total
        float run = le[t];
#pragma unroll
        for (int off = 1; off < 64; off <<= 1) {
            float o = __shfl_up(run, off, 64);
            if (t >= off) run += o;
        }
        ecum[t] = run;
        if (t == 63) pubf(&Tcs[b], run);
    }
    publish_flag(&f2[b], t);

    // ---------------- layer-2 lookback ----------------
    wait_n(&f2[s * NC], c, t);

    // ---------------- Phase D: scomp, stB, KVT MFMA ----------------
    if (t < 64) {
        float v = (t < c) ? rdf(&Tcs[s * NC + t]) : 0.f;
        v = waveRed(v);
        if (t == 0) pcsv = v;
    }
    __syncthreads();
    if (t < 64) {
        int l = c * C + t;
        lsc[t] = le[t] * rcpf(pcsv + ecum[t]) * (float)(l + 1);
    }
    __syncthreads();

    {   // masked P*scomp -> stB (bf16); identical values to k_final's P-recompute path
        int i = t >> 2, g = t & 3;
        unsigned int wds[8];
#pragma unroll
        for (int p = 0; p < 8; p++) {
            int j0 = g * 16 + 2 * p;
            float v0 = (j0     <= i) ? P[i * SRP + j0]     * lsc[j0]     : 0.f;
            float v1 = (j0 + 1 <= i) ? P[i * SRP + j0 + 1] * lsc[j0 + 1] : 0.f;
            wds[p] = pack2(v0, v1);
        }
        *(uint4*)&stB[i * SB + g * 16]     = make_uint4(wds[0], wds[1], wds[2], wds[3]);
        *(uint4*)&stB[i * SB + g * 16 + 8] = make_uint4(wds[4], wds[5], wds[6], wds[7]);
    }
    __syncthreads();    // P consumption complete; Pun region reusable

    unsigned short* skT = (unsigned short*)Pun;            // [d][i], 9216 B
    unsigned short* vsV = (unsigned short*)(Pun + 2304);   // scomp-scaled V^T, 9216 B
#pragma unroll
    for (int j = 0; j < 2; j++) {   // vsV[m][i] = bf16(raw * lsc[i])
        int flat = 8 * t + 2048 * j, dR = flat >> 6, i0 = flat & 63;
        uint4 vv = *(const uint4*)&vsT[dR * SB + i0];
        float x[8];
        unpack8(vv, x);
#pragma unroll
        for (int u = 0; u < 8; u++) x[u] *= lsc[i0 + u];
        uint4 o;
        o.x = pack2(x[0], x[1]); o.y = pack2(x[2], x[3]);
        o.z = pack2(x[4], x[5]); o.w = pack2(x[6], x[7]);
        *(uint4*)&vsV[dR * SB + i0] = o;
    }
    {   // skB -> skT bit-shuffle transpose
        int i0 = (t & 15) * 4, dt = (t >> 4) * 4;
        uint2 kr[4];
#pragma unroll
        for (int r = 0; r < 4; r++) kr[r] = *(const uint2*)&skB[(i0 + r) * SB + dt];
#pragma unroll
        for (int u = 0; u < 4; u++) {
            unsigned int e0 = (u < 2 ? kr[0].x : kr[0].y), e1 = (u < 2 ? kr[1].x : kr[1].y);
            unsigned int e2 = (u < 2 ? kr[2].x : kr[2].y), e3 = (u < 2 ? kr[3].x : kr[3].y);
            int sh = (u & 1) * 16;
            unsigned int lo = ((e0 >> sh) & 0xffffu) | (((e1 >> sh) & 0xffffu) << 16);
            unsigned int hi = ((e2 >> sh) & 0xffffu) | (((e3 >> sh) & 0xffffu) << 16);
            *(uint2*)&skT[(dt + u) * SB + i0] = make_uint2(lo, hi);
        }
    }
    __syncthreads();

    {   // MFMA: KVT[m][d] = sum_i vsV[m][i] * skT[d][i]; agent-scope stores (LLC-visible)
        f32x4 acc[4] = {{0,0,0,0},{0,0,0,0},{0,0,0,0},{0,0,0,0}};
#pragma unroll
        for (int kk = 0; kk < 64; kk += 32) {
            short8 a = *(const short8*)&vsV[(I0 + mf) * SB + kk + qq * 8];
#pragma unroll
            for (int J = 0; J < 4; J++) {
                short8 bb = *(const short8*)&skT[(16 * J + mf) * SB + kk + qq * 8];
                acc[J] = MFMA16(a, bb, acc[J]);
            }
        }
#pragma unroll
        for (int J = 0; J < 4; J++)
#pragma unroll
            for (int r = 0; r < 4; r++)
                pubf(&KVT[(size_t)b * 4096 + (I0 + 4 * qq + r) * 64 + 16 * J + mf],
                     acc[J][r]);
    }
    publish_flag(&f3[b], t);

    // ---------------- Phase E: KVT exclusive prefix (blocks 0..127) ----------------
    if (b < 128) {
        int sp = b >> 3, sub = b & 7;
        wait_n(&f3[sp * NC], NC, t);
        int e0 = sub * 512 + 2 * t;
        float2 x[NC];
#pragma unroll
        for (int cp = 0; cp < NC; cp++) {
            unsigned long long v = rd64(&KVT[(size_t)(sp * NC + cp) * 4096 + e0]);
            x[cp].x = __uint_as_float((unsigned int)v);
            x[cp].y = __uint_as_float((unsigned int)(v >> 32));
        }
        float r0 = 0.f, r1 = 0.f;
#pragma unroll
        for (int cp = 0; cp < NC; cp++) {
            pubu((unsigned int*)&KVpb[(size_t)(sp * NC + cp) * 4096 + e0], pack2(r0, r1));
            r0 += x[cp].x; r1 += x[cp].y;
        }
        publish_flag(&f4[b], t);
    }

    // ---------------- Phase F: final two MFMAs + output ----------------
    wait_n(&f4[8 * s], 8, t);
    unsigned long long kvp[4];
    size_t base = (size_t)b * 4096;
#pragma unroll
    for (int j = 0; j < 2; j++) {
        kvp[2 * j]     = rd64(&KVpb[base + 8 * t + 2048 * j]);
        kvp[2 * j + 1] = rd64(&KVpb[base + 8 * t + 2048 * j + 4]);
    }
#pragma unroll
    for (int j = 0; j < 2; j++) {   // overlay KV-prefix rows [m][d] onto skB
        int flat = 8 * t + 2048 * j, i = flat >> 6, d0 = flat & 63;
        *(uint2*)&skB[i * SB + d0] =
            make_uint2((unsigned int)kvp[2 * j], (unsigned int)(kvp[2 * j] >> 32));
        *(uint2*)&skB[i * SB + d0 + 4] =
            make_uint2((unsigned int)kvp[2 * j + 1], (unsigned int)(kvp[2 * j + 1] >> 32));
    }
    __syncthreads();

    {
        f32x4 acc[4] = {{0,0,0,0},{0,0,0,0},{0,0,0,0},{0,0,0,0}};
#pragma unroll
        for (int kk = 0; kk < 64; kk += 32) {   // mm1: sq · KVp ; mm2: stB · v
            short8 a1 = *(const short8*)&sqB[(I0 + mf) * SB + kk + qq * 8];
            short8 a2 = *(const short8*)&stB[(I0 + mf) * SB + kk + qq * 8];
#pragma unroll
            for (int J = 0; J < 4; J++) {
                short8 b1 = *(const short8*)&skB[(16 * J + mf) * SB + kk + qq * 8];
                acc[J] = MFMA16(a1, b1, acc[J]);
                short8 b2 = *(const short8*)&vsT[(16 * J + mf) * SB + kk + qq * 8];
                acc[J] = MFMA16(a2, b2, acc[J]);
            }
        }
#pragma unroll
        for (int J = 0; J < 4; J++)
#pragma unroll
            for (int r = 0; r < 4; r++) {
                int io = I0 + 4 * qq + r;
                Out[gidx(n, c * C + io, h, 16 * J + mf)] = acc[J][r] * s2l[io];
            }
    }
}

extern "C" void kernel_launch(void* const* d_in, const int* in_sizes, int n_in,
                              void* d_out, int out_size, void* d_ws, size_t ws_size,
                              hipStream_t stream) {
    const float* Q = (const float*)d_in[0];
    const float* K = (const float*)d_in[1];
    const float* V = (const float*)d_in[2];
    float* Out = (float*)d_out;

    float* ws   = (float*)d_ws;
    float* SK   = ws;                   // SC*64
    float* SQ   = SK   + SC * 64;
    float* SKso = SQ   + SC * 64;
    float* SQsi = SKso + SC * 64;
    float* Tcs  = SQsi + SC * 64;       // SC
    float* KVT  = Tcs  + SC;            // SC*4096 f32
    unsigned short* KVpb = (unsigned short*)(KVT + (size_t)SC * 4096);  // SC*4096 bf16
    unsigned int* f0 = (unsigned int*)(KVpb + (size_t)SC * 4096);       // SC
    unsigned int* f1 = f0 + SC;
    unsigned int* f2 = f1 + SC;
    unsigned int* f3 = f2 + SC;
    unsigned int* f4 = f3 + SC;         // 128 used

    k_all<<<SC, 256, 0, stream>>>(Q, K, V, SK, SQ, SKso, SQsi, Tcs, KVT, KVpb, Out,
                                  f0, f1, f2, f3, f4);
}